// Round 13
// baseline (1551.439 us; speedup 1.0000x reference)
//
#include <hip/hip_runtime.h>

#define DEVINL __device__ __forceinline__

typedef __attribute__((ext_vector_type(8))) short bf16x8;
typedef __attribute__((ext_vector_type(4))) float f32x4;

DEVINL void fma4(float4& a, const float4 w, const float x) {
    a.x += w.x * x; a.y += w.y * x; a.z += w.z * x; a.w += w.w * x;
}

DEVINL unsigned short bf16of(float x) {
    unsigned a = __float_as_uint(x);
    a += 0x7FFFu + ((a >> 16) & 1u);
    return (unsigned short)(a >> 16);
}

// pack two fp32 into one u32 of 2 bf16 (RNE); element "lo" in low half
DEVINL unsigned bfpair(float lo, float hi) {
    unsigned a = __float_as_uint(lo);
    a += 0x7FFFu + ((a >> 16) & 1u);
    unsigned b = __float_as_uint(hi);
    b += 0x7FFFu + ((b >> 16) & 1u);
    return (a >> 16) | (b & 0xFFFF0000u);
}

DEVINL float bflo(unsigned u) { return __uint_as_float(u << 16); }
DEVINL float bfhi(unsigned u) { return __uint_as_float(u & 0xFFFF0000u); }

DEVINL bf16x8 as_bf16x8(uint4 u) {
    union { uint4 u4; bf16x8 b; } cv; cv.u4 = u; return cv.b;
}

// ===========================================================================
// CSR build: counting sort of edges by dst. Payload = int4 {eid,dst,src,0}.
// ===========================================================================
__global__ __launch_bounds__(256) void hist_kernel(const int* __restrict__ d,
                                                   int* __restrict__ counts, int n) {
    for (int i = blockIdx.x * 256 + threadIdx.x; i < n; i += gridDim.x * 256)
        atomicAdd(&counts[d[i]], 1);
}

__global__ __launch_bounds__(1024) void scan_block(const int* __restrict__ in,
                                                   int* __restrict__ out,
                                                   int* __restrict__ bsums, int n) {
    __shared__ int buf[2][1024];
    const int t = threadIdx.x;
    const int i = blockIdx.x * 1024 + t;
    const int v = (i < n) ? in[i] : 0;
    int cur = 0;
    buf[0][t] = v;
    __syncthreads();
    #pragma unroll
    for (int s = 1; s < 1024; s <<= 1) {
        int x = buf[cur][t];
        if (t >= s) x += buf[cur][t - s];
        buf[cur ^ 1][t] = x;
        cur ^= 1;
        __syncthreads();
    }
    if (i < n) out[i] = buf[cur][t] - v;            // exclusive
    if (t == 1023) bsums[blockIdx.x] = buf[cur][t]; // block total
}

__global__ void scan_small(int* __restrict__ bs, int nb) {
    if (blockIdx.x == 0 && threadIdx.x == 0) {
        int acc = 0;
        for (int i = 0; i < nb; i++) { int v = bs[i]; bs[i] = acc; acc += v; }
    }
}

__global__ __launch_bounds__(1024) void add_offsets(int* __restrict__ out,
                                                    const int* __restrict__ bs, int n) {
    int i = blockIdx.x * 1024 + threadIdx.x;
    if (i < n) out[i] += bs[blockIdx.x];
}

__global__ __launch_bounds__(256) void scatter_kernel(const int* __restrict__ d,
                                                      const int* __restrict__ src,
                                                      int* __restrict__ cursor,
                                                      int4* __restrict__ recs, int n) {
    for (int i = blockIdx.x * 256 + threadIdx.x; i < n; i += gridDim.x * 256) {
        int dd = d[i];
        int ss = src[i];
        int pos = atomicAdd(&cursor[dd], 1);
        recs[pos] = make_int4(i, dd, ss, 0);
    }
}

// ===========================================================================
// pack_we (fp32, fallback path): e-part rows -> padded [64][FOUTP].
// ===========================================================================
template<int FIN, int FOUT, int FOUTP>
__global__ __launch_bounds__(256) void pack_we(const float* __restrict__ W,
                                               float* __restrict__ Wp) {
    int idx = blockIdx.x * 256 + threadIdx.x;
    if (idx >= 64 * FOUTP) return;
    int k = idx / FOUTP, j = idx - k * FOUTP;
    Wp[idx] = (j < FOUT) ? W[(FIN + k) * FOUT + j] : 0.f;
}

// ===========================================================================
// pack_wbt: e-part of Wm -> bf16 TRANSPOSED table WbT[col][64], col padded
// to NC with zeros. Row stride 64 bf16 = 128B.
// ===========================================================================
template<int FIN, int FOUT, int NC>
__global__ __launch_bounds__(256) void pack_wbt(const float* __restrict__ W,
                                                unsigned short* __restrict__ WbT) {
    int idx = blockIdx.x * 256 + threadIdx.x;
    if (idx >= NC * 64) return;
    int c = idx / 64, k = idx - c * 64;
    WbT[idx] = (c < FOUT) ? bf16of(W[(FIN + k) * FOUT + c]) : (unsigned short)0;
}

// ===========================================================================
// gemv_g: g = x @ W(h-part rows [0,FIN)) + b, padded to FOUTP.
// ===========================================================================
template<int FIN, int FOUT, int FOUTP>
__global__ __launch_bounds__(256) void gemv_g(
    const float* __restrict__ x,
    const float* __restrict__ W,
    const float* __restrict__ b,
    float* __restrict__ g, int nNodes)
{
    constexpr int F4 = FOUTP / 4;
    __shared__ float4 Wl[FIN * F4];
    __shared__ float  bl[FOUTP];
    const int tid = threadIdx.x;
    for (int idx = tid; idx < FIN * FOUTP; idx += 256) {
        int k = idx / FOUTP, j = idx - k * FOUTP;
        reinterpret_cast<float*>(Wl)[idx] = (j < FOUT) ? W[k * FOUT + j] : 0.f;
    }
    for (int idx = tid; idx < FOUTP; idx += 256)
        bl[idx] = (idx < FOUT) ? b[idx] : 0.f;
    __syncthreads();
    const int n = blockIdx.x * 256 + tid;
    if (n >= nNodes) return;
    float4 acc[F4];
    #pragma unroll
    for (int j4 = 0; j4 < F4; j4++) acc[j4] = reinterpret_cast<float4*>(bl)[j4];
    const float* xr = x + (long long)n * FIN;
    #pragma unroll 1
    for (int k = 0; k < FIN; ++k) {
        float xk = xr[k];
        const float4* wrow = &Wl[k * F4];
        #pragma unroll
        for (int j4 = 0; j4 < F4; j4++) fma4(acc[j4], wrow[j4], xk);
    }
    float4* gr = reinterpret_cast<float4*>(g + (long long)n * FOUTP);
    #pragma unroll
    for (int j4 = 0; j4 < F4; j4++) gr[j4] = acc[j4];
}

// ===========================================================================
// Layer-1 edge kernel (fused): per 16-row tile,
//   gather fp32 e-row -> bf16 A-frags (in-register),
//   ep1 = e@We1 -> m1 = relu(g1[src]+ep1) -> msg tile -> segmented reduce,
//   ep2 = e@We2, ep3 = e@We3 -> packed bf16 D-fragment blobs (lane-coalesced
//   uint4 stores) consumed by layers 2/3 (NO e re-read, NO MFMA there).
// MFMA frag semantics (HW-verified r11): A lane row=l&15,k=(l>>4)*8+j;
// B lane col=l&15; D lane col=l&15,row=(l>>4)*4+reg.
// ===========================================================================
__global__ __launch_bounds__(256) void edge_mfma_all(
    const float* __restrict__ g,          // [N][52]
    const float* __restrict__ efeats,
    const int4* __restrict__ recs,        // sorted {eid,dst,src,0}
    const unsigned short* __restrict__ Wb1, // [64][64] bf16^T
    const unsigned short* __restrict__ Wb2, // [32][64]
    const unsigned short* __restrict__ Wb3, // [32][64]
    unsigned* __restrict__ ep2,           // [E/16][64] uint4 frag blobs
    unsigned* __restrict__ ep3,
    float* __restrict__ agg)
{
    constexpr int FOUT = 50, FOUTP = 52, NT = 4;
    constexpr int MS = NT * 16 + 1;

    __shared__ float msg[4][32 * MS];
    __shared__ int eidL[512], sIdxL[512], dseg[512];

    const int tid = threadIdx.x;
    const long long pb = (long long)blockIdx.x * 512;
    {
        int4 r0 = recs[pb + tid];
        int4 r1 = recs[pb + 256 + tid];
        eidL[tid] = r0.x;  dseg[tid] = r0.y;  sIdxL[tid] = r0.z;
        eidL[tid + 256] = r1.x; dseg[tid + 256] = r1.y; sIdxL[tid + 256] = r1.z;
    }
    __syncthreads();

    const int lane = tid & 63;
    const int wv   = tid >> 6;
    const int lg   = lane >> 4;
    const int lc   = lane & 15;

    bf16x8 bfr1[2][4], bfr2[2][2], bfr3[2][2];
    #pragma unroll
    for (int kt = 0; kt < 2; kt++) {
        #pragma unroll
        for (int nt = 0; nt < 4; nt++)
            bfr1[kt][nt] = *reinterpret_cast<const bf16x8*>(Wb1 + (nt * 16 + lc) * 64 + kt * 32 + lg * 8);
        #pragma unroll
        for (int nt = 0; nt < 2; nt++) {
            bfr2[kt][nt] = *reinterpret_cast<const bf16x8*>(Wb2 + (nt * 16 + lc) * 64 + kt * 32 + lg * 8);
            bfr3[kt][nt] = *reinterpret_cast<const bf16x8*>(Wb3 + (nt * 16 + lc) * 64 + kt * 32 + lg * 8);
        }
    }

    float* msgW = msg[wv];

    #pragma unroll 1
    for (int ch = 0; ch < 4; ++ch) {
        const int rb0 = wv * 128 + ch * 32;
        #pragma unroll 1
        for (int mt = 0; mt < 2; ++mt) {
            const int rowbase = rb0 + mt * 16;
            const long long tix = (pb >> 4) + wv * 8 + ch * 2 + mt;  // 16-row tile idx
            // gather fp32 row (4 lanes x 64B cover the 256B row once)
            const int eid = eidL[rowbase + lc];
            const float4* erow = reinterpret_cast<const float4*>(efeats + (long long)eid * 64);
            float4 f0 = erow[lg * 2];
            float4 f1 = erow[lg * 2 + 1];
            float4 f2 = erow[8 + lg * 2];
            float4 f3 = erow[8 + lg * 2 + 1];
            uint4 u0, u1;
            u0.x = bfpair(f0.x, f0.y); u0.y = bfpair(f0.z, f0.w);
            u0.z = bfpair(f1.x, f1.y); u0.w = bfpair(f1.z, f1.w);
            u1.x = bfpair(f2.x, f2.y); u1.y = bfpair(f2.z, f2.w);
            u1.z = bfpair(f3.x, f3.y); u1.w = bfpair(f3.z, f3.w);
            bf16x8 a0 = as_bf16x8(u0);
            bf16x8 a1 = as_bf16x8(u1);

            int sr[4];
            #pragma unroll
            for (int r = 0; r < 4; r++) sr[r] = sIdxL[rowbase + lg * 4 + r];

            // ---- ep1 -> m1 into msg tile ----
            #pragma unroll
            for (int nt = 0; nt < 4; nt++) {
                f32x4 acc = {0.f, 0.f, 0.f, 0.f};
                acc = __builtin_amdgcn_mfma_f32_16x16x32_bf16(a0, bfr1[0][nt], acc, 0, 0, 0);
                acc = __builtin_amdgcn_mfma_f32_16x16x32_bf16(a1, bfr1[1][nt], acc, 0, 0, 0);
                const int col = nt * 16 + lc;
                #pragma unroll
                for (int r = 0; r < 4; r++) {
                    float gv = (col < FOUT) ? g[(long long)sr[r] * FOUTP + col] : 0.f;
                    msgW[(mt * 16 + lg * 4 + r) * MS + col] = fmaxf(acc[r] + gv, 0.f);
                }
            }
            // ---- ep2 -> packed D-frag blob (lane-coalesced uint4) ----
            {
                uint4 st;
                #pragma unroll
                for (int nt = 0; nt < 2; nt++) {
                    f32x4 acc = {0.f, 0.f, 0.f, 0.f};
                    acc = __builtin_amdgcn_mfma_f32_16x16x32_bf16(a0, bfr2[0][nt], acc, 0, 0, 0);
                    acc = __builtin_amdgcn_mfma_f32_16x16x32_bf16(a1, bfr2[1][nt], acc, 0, 0, 0);
                    unsigned w0 = bfpair(acc[0], acc[1]);
                    unsigned w1 = bfpair(acc[2], acc[3]);
                    if (nt == 0) { st.x = w0; st.y = w1; } else { st.z = w0; st.w = w1; }
                }
                reinterpret_cast<uint4*>(ep2)[tix * 64 + lane] = st;
            }
            // ---- ep3 -> packed D-frag blob ----
            {
                uint4 st;
                #pragma unroll
                for (int nt = 0; nt < 2; nt++) {
                    f32x4 acc = {0.f, 0.f, 0.f, 0.f};
                    acc = __builtin_amdgcn_mfma_f32_16x16x32_bf16(a0, bfr3[0][nt], acc, 0, 0, 0);
                    acc = __builtin_amdgcn_mfma_f32_16x16x32_bf16(a1, bfr3[1][nt], acc, 0, 0, 0);
                    unsigned w0 = bfpair(acc[0], acc[1]);
                    unsigned w1 = bfpair(acc[2], acc[3]);
                    if (nt == 0) { st.x = w0; st.y = w1; } else { st.z = w0; st.w = w1; }
                }
                reinterpret_cast<uint4*>(ep3)[tix * 64 + lane] = st;
            }
        }
        // segmented reduce over this chunk's 32 rows (same-wave LDS)
        const int base = rb0;
        for (int r0 = 0; r0 < 32; ++r0) {
            int dr = dseg[base + r0];
            if (r0 > 0 && dseg[base + r0 - 1] == dr) continue;
            float s = 0.f;
            int rr = r0;
            while (true) {
                s += msgW[rr * MS + lane];
                ++rr;
                if (rr >= 32 || dseg[base + rr] != dr) break;
            }
            if (lane < FOUT) atomicAdd(agg + (long long)dr * FOUT + lane, s);
        }
    }
}

// ===========================================================================
// Layers 2/3 edge kernel: NO MFMA, NO e. Reads the packed ep blob (one
// coalesced uint4 per lane per 16-row tile), unpacks 8 bf16 (2 cols x 4
// rows, D-frag layout mirrored from edge_mfma_all), adds gathered g[src],
// relu, msg tile, segmented reduce.
// ===========================================================================
template<int FOUT, int FOUTP>
__global__ __launch_bounds__(256) void edge_ep(
    const float* __restrict__ g,
    const unsigned* __restrict__ ep,     // [E/16][64] uint4 frag blobs
    const int4* __restrict__ recs,
    float* __restrict__ agg)
{
    constexpr int NT = 2;
    constexpr int MS = NT * 16 + 1;

    __shared__ float msg[4][32 * MS];
    __shared__ int sIdxL[512], dseg[512];

    const int tid = threadIdx.x;
    const long long pb = (long long)blockIdx.x * 512;
    {
        int4 r0 = recs[pb + tid];
        int4 r1 = recs[pb + 256 + tid];
        dseg[tid] = r0.y;  sIdxL[tid] = r0.z;
        dseg[tid + 256] = r1.y; sIdxL[tid + 256] = r1.z;
    }
    __syncthreads();

    const int lane = tid & 63;
    const int wv   = tid >> 6;
    const int lg   = lane >> 4;
    const int lc   = lane & 15;

    float* msgW = msg[wv];

    #pragma unroll 1
    for (int ch = 0; ch < 4; ++ch) {
        const int rb0 = wv * 128 + ch * 32;
        #pragma unroll
        for (int mt = 0; mt < 2; ++mt) {
            const int rowbase = rb0 + mt * 16;
            const long long tix = (pb >> 4) + wv * 8 + ch * 2 + mt;
            uint4 v = reinterpret_cast<const uint4*>(ep)[tix * 64 + lane];

            int sr[4];
            #pragma unroll
            for (int r = 0; r < 4; r++) sr[r] = sIdxL[rowbase + lg * 4 + r];

            #pragma unroll
            for (int nt = 0; nt < 2; nt++) {
                float e0 = bflo(nt == 0 ? v.x : v.z);
                float e1 = bfhi(nt == 0 ? v.x : v.z);
                float e2 = bflo(nt == 0 ? v.y : v.w);
                float e3 = bfhi(nt == 0 ? v.y : v.w);
                const int col = nt * 16 + lc;
                float ev[4] = {e0, e1, e2, e3};
                #pragma unroll
                for (int r = 0; r < 4; r++) {
                    float gv = (col < FOUT) ? g[(long long)sr[r] * FOUTP + col] : 0.f;
                    msgW[(mt * 16 + lg * 4 + r) * MS + col] = fmaxf(ev[r] + gv, 0.f);
                }
            }
        }
        const int base = rb0;
        for (int r0 = 0; r0 < 32; ++r0) {
            int dr = dseg[base + r0];
            if (r0 > 0 && dseg[base + r0 - 1] == dr) continue;
            float s = 0.f;
            int rr = r0;
            while (true) {
                s += msgW[rr * MS + lane];
                ++rr;
                if (rr >= 32 || dseg[base + rr] != dr) break;
            }
            if (lane < FOUT) atomicAdd(agg + (long long)dr * FOUT + lane, s);
        }
    }
}

// ===========================================================================
// FALLBACK edge kernel (ws too small for ep2/ep3): round-10 proven structure.
// ===========================================================================
template<int FOUT, int FOUTP, int MS>
__global__ __launch_bounds__(256) void edge_fb(
    const float* __restrict__ g,
    const float* __restrict__ efeats,
    const int4* __restrict__ recs,
    const float* __restrict__ Wp,
    float* __restrict__ agg)
{
    constexpr int F4 = FOUTP / 4;
    constexpr int ST = 17;
    static_assert(128 * MS + 64 <= 512 * ST, "msg buf exceeds sbuf");

    __shared__ float sbuf[512 * ST];
    __shared__ int   dseg[512];

    const int tid = threadIdx.x;
    const long long pb = (long long)blockIdx.x * 512;
    int4 r0 = recs[pb + tid];
    int4 r1 = recs[pb + 256 + tid];
    dseg[tid] = r0.y;
    dseg[tid + 256] = r1.y;

    const float4* gr0 = reinterpret_cast<const float4*>(g + (long long)r0.z * FOUTP);
    const float4* gr1 = reinterpret_cast<const float4*>(g + (long long)r1.z * FOUTP);
    const float*  er0 = efeats + (long long)r0.x * 64;
    const float*  er1 = efeats + (long long)r1.x * 64;
    const float4* Wp4 = reinterpret_cast<const float4*>(Wp);

    float4 acc0[F4], acc1[F4];
    #pragma unroll
    for (int j4 = 0; j4 < F4; j4++) acc0[j4] = gr0[j4];
    #pragma unroll
    for (int j4 = 0; j4 < F4; j4++) acc1[j4] = gr1[j4];

    const int t0 = tid * ST;
    const int t1 = (tid + 256) * ST;

    for (int c = 0; c < 4; ++c) {
        const int off = c * 16;
        #pragma unroll
        for (int f = 0; f < 4; ++f) {
            float4 v0 = *reinterpret_cast<const float4*>(er0 + off + 4 * f);
            float4 v1 = *reinterpret_cast<const float4*>(er1 + off + 4 * f);
            float* d0 = &sbuf[t0 + 4 * f];
            float* d1 = &sbuf[t1 + 4 * f];
            d0[0] = v0.x; d0[1] = v0.y; d0[2] = v0.z; d0[3] = v0.w;
            d1[0] = v1.x; d1[1] = v1.y; d1[2] = v1.z; d1[3] = v1.w;
        }
        #pragma unroll 1
        for (int k = 0; k < 16; ++k) {
            const float x0 = sbuf[t0 + k];
            const float x1 = sbuf[t1 + k];
            const float4* wrow = &Wp4[(off + k) * F4];
            #pragma unroll
            for (int j4 = 0; j4 < F4; j4++) {
                float4 w = wrow[j4];
                fma4(acc0[j4], w, x0);
                fma4(acc1[j4], w, x1);
            }
        }
    }

    const int lane = tid & 63;
    const int wv   = tid >> 6;

    #pragma unroll 1
    for (int bb = 0; bb < 4; ++bb) {
        __syncthreads();
        if ((tid >> 7) == (bb & 1)) {
            const int r = tid & 127;
            float* mrow = &sbuf[r * MS];
            const float4* accp = (bb < 2) ? acc0 : acc1;
            #pragma unroll
            for (int j4 = 0; j4 < F4; j4++) {
                float4 a = accp[j4];
                if (4 * j4 + 0 < FOUT) mrow[4 * j4 + 0] = fmaxf(a.x, 0.f);
                if (4 * j4 + 1 < FOUT) mrow[4 * j4 + 1] = fmaxf(a.y, 0.f);
                if (4 * j4 + 2 < FOUT) mrow[4 * j4 + 2] = fmaxf(a.z, 0.f);
                if (4 * j4 + 3 < FOUT) mrow[4 * j4 + 3] = fmaxf(a.w, 0.f);
            }
        }
        __syncthreads();

        const int rbase = bb * 128;
        for (int r0i = wv * 32; r0i < wv * 32 + 32; ++r0i) {
            int dr = dseg[rbase + r0i];
            if (r0i > 0 && dseg[rbase + r0i - 1] == dr) continue;
            float s = 0.f;
            int rr = r0i;
            while (true) {
                s += sbuf[rr * MS + lane];
                ++rr;
                if (rr >= 128 || dseg[rbase + rr] != dr) break;
            }
            if (lane < FOUT) atomicAdd(agg + (long long)dr * FOUT + lane, s);
        }
    }
}

// ===========================================================================
// Node kernel (fused): h_next = relu(cat(h, agg) @ Wa + ba), plus fused
// g_next = h_next @ Wm_next(h-part) + bm_next when GOUT > 0.
// ===========================================================================
template<int FH, int FHP, int FAGG, int FOUT, int FOUTP, int GOUT, int GOUTP>
__global__ __launch_bounds__(256) void node_kernel(
    const float* __restrict__ h,
    const float* __restrict__ agg,
    const float* __restrict__ Wa,
    const float* __restrict__ ba,
    const float* __restrict__ Wmn,
    const float* __restrict__ bmn,
    float* __restrict__ out,
    float* __restrict__ gout,
    int nNodes)
{
    constexpr int K  = FH + FAGG;
    constexpr int F4 = FOUTP / 4;
    constexpr int G4 = (GOUT > 0) ? GOUTP / 4 : 1;

    __shared__ float4 Wl[K * F4];
    __shared__ float4 Wg[(GOUT > 0) ? FOUTP * G4 : 1];
    __shared__ float  bl[FOUTP];
    __shared__ float  bg[(GOUT > 0) ? GOUTP : 4];

    const int tid = threadIdx.x;
    for (int idx = tid; idx < K * FOUTP; idx += 256) {
        int k = idx / FOUTP, j = idx - k * FOUTP;
        reinterpret_cast<float*>(Wl)[idx] = (j < FOUT) ? Wa[k * FOUT + j] : 0.f;
    }
    for (int idx = tid; idx < FOUTP; idx += 256)
        bl[idx] = (idx < FOUT) ? ba[idx] : 0.f;
    if constexpr (GOUT > 0) {
        for (int idx = tid; idx < FOUTP * GOUTP; idx += 256) {
            int k = idx / GOUTP, j = idx - k * GOUTP;
            reinterpret_cast<float*>(Wg)[idx] =
                (k < FOUT && j < GOUT) ? Wmn[k * GOUT + j] : 0.f;
        }
        for (int idx = tid; idx < GOUTP; idx += 256)
            bg[idx] = (idx < GOUT) ? bmn[idx] : 0.f;
    }
    __syncthreads();

    const int n = blockIdx.x * 256 + tid;
    if (n >= nNodes) return;

    float4 acc[F4];
    #pragma unroll
    for (int j4 = 0; j4 < F4; j4++) acc[j4] = reinterpret_cast<float4*>(bl)[j4];

    const float* hrow = h + (long long)n * FHP;
    #pragma unroll 1
    for (int k = 0; k < FH; k++) {
        float xk = hrow[k];
        const float4* wrow = &Wl[k * F4];
        #pragma unroll
        for (int j4 = 0; j4 < F4; j4++) fma4(acc[j4], wrow[j4], xk);
    }
    const float* arow = agg + (long long)n * FAGG;
    #pragma unroll 1
    for (int k = 0; k < FAGG; k++) {
        float xk = arow[k];
        const float4* wrow = &Wl[(FH + k) * F4];
        #pragma unroll
        for (int j4 = 0; j4 < F4; j4++) fma4(acc[j4], wrow[j4], xk);
    }

    #pragma unroll
    for (int j4 = 0; j4 < F4; j4++) {
        acc[j4].x = fmaxf(acc[j4].x, 0.f);
        acc[j4].y = fmaxf(acc[j4].y, 0.f);
        acc[j4].z = fmaxf(acc[j4].z, 0.f);
        acc[j4].w = fmaxf(acc[j4].w, 0.f);
    }
    float4* orow = reinterpret_cast<float4*>(out + (long long)n * FOUTP);
    #pragma unroll
    for (int j4 = 0; j4 < F4; j4++) orow[j4] = acc[j4];

    if constexpr (GOUT > 0) {
        float4 gacc[G4];
        #pragma unroll
        for (int j4 = 0; j4 < G4; j4++) gacc[j4] = reinterpret_cast<float4*>(bg)[j4];
        #pragma unroll 1
        for (int k4 = 0; k4 < F4; ++k4) {
            float4 xv = acc[k4];
            #pragma unroll
            for (int c = 0; c < 4; ++c) {
                float xc = (c == 0) ? xv.x : (c == 1) ? xv.y : (c == 2) ? xv.z : xv.w;
                const float4* wrow = &Wg[(k4 * 4 + c) * G4];
                #pragma unroll
                for (int j4 = 0; j4 < G4; j4++) fma4(gacc[j4], wrow[j4], xc);
            }
        }
        float4* grow = reinterpret_cast<float4*>(gout + (long long)n * GOUTP);
        #pragma unroll
        for (int j4 = 0; j4 < G4; j4++) grow[j4] = gacc[j4];
    }
}

extern "C" void kernel_launch(void* const* d_in, const int* in_sizes, int n_in,
                              void* d_out, int out_size, void* d_ws, size_t ws_size,
                              hipStream_t stream)
{
    const float* nfeats = (const float*)d_in[0];
    const float* efeats = (const float*)d_in[1];
    const int*   src    = (const int*)d_in[2];
    const int*   dst    = (const int*)d_in[3];
    const float* Wm1 = (const float*)d_in[4],  *bm1 = (const float*)d_in[5];
    const float* Wa1 = (const float*)d_in[6],  *ba1 = (const float*)d_in[7];
    const float* Wm2 = (const float*)d_in[8],  *bm2 = (const float*)d_in[9];
    const float* Wa2 = (const float*)d_in[10], *ba2 = (const float*)d_in[11];
    const float* Wm3 = (const float*)d_in[12], *bm3 = (const float*)d_in[13];
    const float* Wa3 = (const float*)d_in[14], *ba3 = (const float*)d_in[15];
    float* out = (float*)d_out;

    constexpr int N = 100000;
    constexpr int E = 3200000;                      // % 512 == 0
    constexpr int SCAN_BLOCKS = (N + 1023) / 1024;  // 98

    float* ws   = (float*)d_ws;
    float* h1   = ws;                            // N x 52
    float* h2   = h1 + (size_t)N * 52;           // N x 28
    float* agg  = h2 + (size_t)N * 28;           // N x 52
    float* g    = agg + (size_t)N * 52;          // N x 52
    int* counts = (int*)(g + (size_t)N * 52);    // N
    int* cursor = counts + N;                    // N
    int* bsums  = cursor + N;                    // 128
    int4* recs  = (int4*)(bsums + 128);          // E x 16B
    float* Wp1  = (float*)(recs + E);            // 64 x 52 fp32 (fallback)
    float* Wp2  = Wp1 + 64 * 52;                 // 64 x 28
    float* Wp3  = Wp2 + 64 * 28;                 // 64 x 32
    unsigned short* Wb1 = (unsigned short*)(Wp3 + 64 * 32); // 64 x 64 bf16
    unsigned short* Wb2 = Wb1 + 64 * 64;                    // 32 x 64 bf16
    unsigned short* Wb3 = Wb2 + 32 * 64;                    // 32 x 64 bf16
    char* endp = (char*)(Wb3 + 32 * 64);

    size_t usedB  = (size_t)(endp - (char*)d_ws);
    size_t epOffB = (usedB + 127) & ~(size_t)127;
    size_t neededB = epOffB + (size_t)E * 128;   // ep2 (E x 64B) + ep3 (E x 64B)
    const bool useBf = (ws_size >= neededB);
    unsigned* ep2 = (unsigned*)((char*)d_ws + epOffB);
    unsigned* ep3 = ep2 + (size_t)E * 16;        // E x 16 u32 = E x 64B

    // ---- pack W tables ----
    pack_we<64, 50, 52><<<(64 * 52 + 255) / 256, 256, 0, stream>>>(Wm1, Wp1);
    pack_we<50, 25, 28><<<(64 * 28 + 255) / 256, 256, 0, stream>>>(Wm2, Wp2);
    pack_we<25, 32, 32><<<(64 * 32 + 255) / 256, 256, 0, stream>>>(Wm3, Wp3);
    pack_wbt<64, 50, 64><<<(64 * 64 + 255) / 256, 256, 0, stream>>>(Wm1, Wb1);
    pack_wbt<50, 25, 32><<<(32 * 64 + 255) / 256, 256, 0, stream>>>(Wm2, Wb2);
    pack_wbt<25, 32, 32><<<(32 * 64 + 255) / 256, 256, 0, stream>>>(Wm3, Wb3);

    // ---- CSR build (counting sort by dst; payload = int4 record) ----
    hipMemsetAsync(counts, 0, (size_t)N * sizeof(int), stream);
    hist_kernel<<<2048, 256, 0, stream>>>(dst, counts, E);
    scan_block<<<SCAN_BLOCKS, 1024, 0, stream>>>(counts, cursor, bsums, N);
    scan_small<<<1, 64, 0, stream>>>(bsums, SCAN_BLOCKS);
    add_offsets<<<SCAN_BLOCKS, 1024, 0, stream>>>(cursor, bsums, N);
    scatter_kernel<<<2048, 256, 0, stream>>>(dst, src, cursor, recs, E);

    const int EB = E / 512;
    const int NB = (N + 255) / 256;

    // ---- g1 = nfeats @ Wm1(h-part) + bm1 ----
    gemv_g<64, 50, 52><<<NB, 256, 0, stream>>>(nfeats, Wm1, bm1, g, N);

    // ---- layer 1 (computes ep2/ep3 for layers 2/3 in the same pass) ----
    hipMemsetAsync(agg, 0, (size_t)N * 52 * sizeof(float), stream);
    if (useBf)
        edge_mfma_all<<<EB, 256, 0, stream>>>(g, efeats, recs, Wb1, Wb2, Wb3, ep2, ep3, agg);
    else
        edge_fb<50, 52, 51><<<EB, 256, 0, stream>>>(g, efeats, recs, Wp1, agg);
    node_kernel<64, 64, 50, 50, 52, 25, 28><<<NB, 256, 0, stream>>>(
        nfeats, agg, Wa1, ba1, Wm2, bm2, h1, g, N);

    // ---- layer 2 (pure stream + gather + reduce) ----
    hipMemsetAsync(agg, 0, (size_t)N * 52 * sizeof(float), stream);
    if (useBf)
        edge_ep<25, 28><<<EB, 256, 0, stream>>>(g, ep2, recs, agg);
    else
        edge_fb<25, 28, 25><<<EB, 256, 0, stream>>>(g, efeats, recs, Wp2, agg);
    node_kernel<50, 52, 25, 25, 28, 32, 32><<<NB, 256, 0, stream>>>(
        h1, agg, Wa2, ba2, Wm3, bm3, h2, g, N);

    // ---- layer 3 ----
    hipMemsetAsync(agg, 0, (size_t)N * 52 * sizeof(float), stream);
    if (useBf)
        edge_ep<32, 32><<<EB, 256, 0, stream>>>(g, ep3, recs, agg);
    else
        edge_fb<32, 32, 33><<<EB, 256, 0, stream>>>(g, efeats, recs, Wp3, agg);
    node_kernel<25, 28, 32, 32, 32, 0, 0><<<NB, 256, 0, stream>>>(
        h2, agg, Wa3, ba3, nullptr, nullptr, out, nullptr, N);
}

// Round 14
// 1397.784 us; speedup vs baseline: 1.1099x; 1.1099x over previous
//
#include <hip/hip_runtime.h>

#define DEVINL __device__ __forceinline__

typedef __attribute__((ext_vector_type(8))) short bf16x8;
typedef __attribute__((ext_vector_type(4))) float f32x4;

DEVINL void fma4(float4& a, const float4 w, const float x) {
    a.x += w.x * x; a.y += w.y * x; a.z += w.z * x; a.w += w.w * x;
}

DEVINL unsigned short bf16of(float x) {
    unsigned a = __float_as_uint(x);
    a += 0x7FFFu + ((a >> 16) & 1u);
    return (unsigned short)(a >> 16);
}

// pack two fp32 into one u32 of 2 bf16 (RNE); element "lo" in low half
DEVINL unsigned bfpair(float lo, float hi) {
    unsigned a = __float_as_uint(lo);
    a += 0x7FFFu + ((a >> 16) & 1u);
    unsigned b = __float_as_uint(hi);
    b += 0x7FFFu + ((b >> 16) & 1u);
    return (a >> 16) | (b & 0xFFFF0000u);
}

DEVINL float bflo(unsigned u) { return __uint_as_float(u << 16); }
DEVINL float bfhi(unsigned u) { return __uint_as_float(u & 0xFFFF0000u); }

DEVINL bf16x8 as_bf16x8(uint4 u) {
    union { uint4 u4; bf16x8 b; } cv; cv.u4 = u; return cv.b;
}

// ===========================================================================
// CSR build: counting sort of edges by dst. Payload = int4 {eid,dst,src,0}.
// ===========================================================================
__global__ __launch_bounds__(256) void hist_kernel(const int* __restrict__ d,
                                                   int* __restrict__ counts, int n) {
    for (int i = blockIdx.x * 256 + threadIdx.x; i < n; i += gridDim.x * 256)
        atomicAdd(&counts[d[i]], 1);
}

__global__ __launch_bounds__(1024) void scan_block(const int* __restrict__ in,
                                                   int* __restrict__ out,
                                                   int* __restrict__ bsums, int n) {
    __shared__ int buf[2][1024];
    const int t = threadIdx.x;
    const int i = blockIdx.x * 1024 + t;
    const int v = (i < n) ? in[i] : 0;
    int cur = 0;
    buf[0][t] = v;
    __syncthreads();
    #pragma unroll
    for (int s = 1; s < 1024; s <<= 1) {
        int x = buf[cur][t];
        if (t >= s) x += buf[cur][t - s];
        buf[cur ^ 1][t] = x;
        cur ^= 1;
        __syncthreads();
    }
    if (i < n) out[i] = buf[cur][t] - v;            // exclusive
    if (t == 1023) bsums[blockIdx.x] = buf[cur][t]; // block total
}

__global__ void scan_small(int* __restrict__ bs, int nb) {
    if (blockIdx.x == 0 && threadIdx.x == 0) {
        int acc = 0;
        for (int i = 0; i < nb; i++) { int v = bs[i]; bs[i] = acc; acc += v; }
    }
}

__global__ __launch_bounds__(1024) void add_offsets(int* __restrict__ out,
                                                    const int* __restrict__ bs, int n) {
    int i = blockIdx.x * 1024 + threadIdx.x;
    if (i < n) out[i] += bs[blockIdx.x];
}

__global__ __launch_bounds__(256) void scatter_kernel(const int* __restrict__ d,
                                                      const int* __restrict__ src,
                                                      int* __restrict__ cursor,
                                                      int4* __restrict__ recs, int n) {
    for (int i = blockIdx.x * 256 + threadIdx.x; i < n; i += gridDim.x * 256) {
        int dd = d[i];
        int ss = src[i];
        int pos = atomicAdd(&cursor[dd], 1);
        recs[pos] = make_int4(i, dd, ss, 0);
    }
}

// ===========================================================================
// pack_we (fp32, fallback path): e-part rows -> padded [64][FOUTP].
// ===========================================================================
template<int FIN, int FOUT, int FOUTP>
__global__ __launch_bounds__(256) void pack_we(const float* __restrict__ W,
                                               float* __restrict__ Wp) {
    int idx = blockIdx.x * 256 + threadIdx.x;
    if (idx >= 64 * FOUTP) return;
    int k = idx / FOUTP, j = idx - k * FOUTP;
    Wp[idx] = (j < FOUT) ? W[(FIN + k) * FOUT + j] : 0.f;
}

// ===========================================================================
// pack_wbt: e-part of Wm -> bf16 TRANSPOSED table WbT[col][64].
// ===========================================================================
template<int FIN, int FOUT, int NC>
__global__ __launch_bounds__(256) void pack_wbt(const float* __restrict__ W,
                                                unsigned short* __restrict__ WbT) {
    int idx = blockIdx.x * 256 + threadIdx.x;
    if (idx >= NC * 64) return;
    int c = idx / 64, k = idx - c * 64;
    WbT[idx] = (c < FOUT) ? bf16of(W[(FIN + k) * FOUT + c]) : (unsigned short)0;
}

// ===========================================================================
// gemv_g: g = x @ W(h-part rows [0,FIN)) + b, padded to FOUTP.
// ===========================================================================
template<int FIN, int FOUT, int FOUTP>
__global__ __launch_bounds__(256) void gemv_g(
    const float* __restrict__ x,
    const float* __restrict__ W,
    const float* __restrict__ b,
    float* __restrict__ g, int nNodes)
{
    constexpr int F4 = FOUTP / 4;
    __shared__ float4 Wl[FIN * F4];
    __shared__ float  bl[FOUTP];
    const int tid = threadIdx.x;
    for (int idx = tid; idx < FIN * FOUTP; idx += 256) {
        int k = idx / FOUTP, j = idx - k * FOUTP;
        reinterpret_cast<float*>(Wl)[idx] = (j < FOUT) ? W[k * FOUT + j] : 0.f;
    }
    for (int idx = tid; idx < FOUTP; idx += 256)
        bl[idx] = (idx < FOUT) ? b[idx] : 0.f;
    __syncthreads();
    const int n = blockIdx.x * 256 + tid;
    if (n >= nNodes) return;
    float4 acc[F4];
    #pragma unroll
    for (int j4 = 0; j4 < F4; j4++) acc[j4] = reinterpret_cast<float4*>(bl)[j4];
    const float* xr = x + (long long)n * FIN;
    #pragma unroll 1
    for (int k = 0; k < FIN; ++k) {
        float xk = xr[k];
        const float4* wrow = &Wl[k * F4];
        #pragma unroll
        for (int j4 = 0; j4 < F4; j4++) fma4(acc[j4], wrow[j4], xk);
    }
    float4* gr = reinterpret_cast<float4*>(g + (long long)n * FOUTP);
    #pragma unroll
    for (int j4 = 0; j4 < F4; j4++) gr[j4] = acc[j4];
}

// ===========================================================================
// Layer-1 edge kernel, SOFTWARE-PIPELINED:
//   - both tiles' efeats gathers issued up front per chunk
//   - epilogue g-values prefetched into registers BEFORE the MFMA cluster
//   - next chunk's gathers issued BEFORE the serial segmented reduce
// Computes ep1 (-> msg/reduce) and ep2/ep3 (-> packed bf16 D-frag blobs for
// layers 2/3). MFMA frag semantics HW-verified r11.
// ===========================================================================
__global__ __launch_bounds__(256) void edge_mfma_all(
    const float* __restrict__ g,          // [N][52]
    const float* __restrict__ efeats,
    const int4* __restrict__ recs,        // sorted {eid,dst,src,0}
    const unsigned short* __restrict__ Wb1, // [64][64] bf16^T
    const unsigned short* __restrict__ Wb2, // [32][64]
    const unsigned short* __restrict__ Wb3, // [32][64]
    unsigned* __restrict__ ep2,           // [E/16][64] uint4 frag blobs
    unsigned* __restrict__ ep3,
    float* __restrict__ agg)
{
    constexpr int FOUT = 50, FOUTP = 52, NT = 4;
    constexpr int MS = NT * 16 + 1;

    __shared__ float msg[4][32 * MS];
    __shared__ int eidL[512], sIdxL[512], dseg[512];

    const int tid = threadIdx.x;
    const long long pb = (long long)blockIdx.x * 512;
    {
        int4 r0 = recs[pb + tid];
        int4 r1 = recs[pb + 256 + tid];
        eidL[tid] = r0.x;  dseg[tid] = r0.y;  sIdxL[tid] = r0.z;
        eidL[tid + 256] = r1.x; dseg[tid + 256] = r1.y; sIdxL[tid + 256] = r1.z;
    }
    __syncthreads();

    const int lane = tid & 63;
    const int wv   = tid >> 6;
    const int lg   = lane >> 4;
    const int lc   = lane & 15;

    bf16x8 bfr1[2][4], bfr2[2][2], bfr3[2][2];
    #pragma unroll
    for (int kt = 0; kt < 2; kt++) {
        #pragma unroll
        for (int nt = 0; nt < 4; nt++)
            bfr1[kt][nt] = *reinterpret_cast<const bf16x8*>(Wb1 + (nt * 16 + lc) * 64 + kt * 32 + lg * 8);
        #pragma unroll
        for (int nt = 0; nt < 2; nt++) {
            bfr2[kt][nt] = *reinterpret_cast<const bf16x8*>(Wb2 + (nt * 16 + lc) * 64 + kt * 32 + lg * 8);
            bfr3[kt][nt] = *reinterpret_cast<const bf16x8*>(Wb3 + (nt * 16 + lc) * 64 + kt * 32 + lg * 8);
        }
    }

    float* msgW = msg[wv];

    // pipeline: f holds current chunk's raw gathered rows (2 tiles x 4 float4)
    float4 f[2][4];
    {
        const int rb0 = wv * 128;
        #pragma unroll
        for (int mt = 0; mt < 2; mt++) {
            const int eid = eidL[rb0 + mt * 16 + lc];
            const float4* erow = reinterpret_cast<const float4*>(efeats + (long long)eid * 64);
            f[mt][0] = erow[lg * 2];     f[mt][1] = erow[lg * 2 + 1];
            f[mt][2] = erow[8 + lg * 2]; f[mt][3] = erow[8 + lg * 2 + 1];
        }
    }

    #pragma unroll 1
    for (int ch = 0; ch < 4; ++ch) {
        const int rb0 = wv * 128 + ch * 32;

        // ---- prefetch epilogue g-values (overlaps the MFMA cluster) ----
        int srr[2][4];
        #pragma unroll
        for (int mt = 0; mt < 2; mt++)
            #pragma unroll
            for (int r = 0; r < 4; r++)
                srr[mt][r] = sIdxL[rb0 + mt * 16 + lg * 4 + r];
        float gv[2][NT][4];
        #pragma unroll
        for (int mt = 0; mt < 2; mt++)
            #pragma unroll
            for (int nt = 0; nt < NT; nt++) {
                const int col = nt * 16 + lc;
                #pragma unroll
                for (int r = 0; r < 4; r++)
                    gv[mt][nt][r] = (col < FOUT) ? g[(long long)srr[mt][r] * FOUTP + col] : 0.f;
            }

        // ---- compute both tiles ----
        #pragma unroll
        for (int mt = 0; mt < 2; mt++) {
            uint4 u0, u1;
            u0.x = bfpair(f[mt][0].x, f[mt][0].y); u0.y = bfpair(f[mt][0].z, f[mt][0].w);
            u0.z = bfpair(f[mt][1].x, f[mt][1].y); u0.w = bfpair(f[mt][1].z, f[mt][1].w);
            u1.x = bfpair(f[mt][2].x, f[mt][2].y); u1.y = bfpair(f[mt][2].z, f[mt][2].w);
            u1.z = bfpair(f[mt][3].x, f[mt][3].y); u1.w = bfpair(f[mt][3].z, f[mt][3].w);
            bf16x8 a0 = as_bf16x8(u0);
            bf16x8 a1 = as_bf16x8(u1);
            const long long tix = (pb >> 4) + wv * 8 + ch * 2 + mt;

            // ep1 -> msg tile
            #pragma unroll
            for (int nt = 0; nt < 4; nt++) {
                f32x4 acc = {0.f, 0.f, 0.f, 0.f};
                acc = __builtin_amdgcn_mfma_f32_16x16x32_bf16(a0, bfr1[0][nt], acc, 0, 0, 0);
                acc = __builtin_amdgcn_mfma_f32_16x16x32_bf16(a1, bfr1[1][nt], acc, 0, 0, 0);
                const int col = nt * 16 + lc;
                #pragma unroll
                for (int r = 0; r < 4; r++)
                    msgW[(mt * 16 + lg * 4 + r) * MS + col] = fmaxf(acc[r] + gv[mt][nt][r], 0.f);
            }
            // ep2 -> packed D-frag blob
            {
                uint4 st;
                #pragma unroll
                for (int nt = 0; nt < 2; nt++) {
                    f32x4 acc = {0.f, 0.f, 0.f, 0.f};
                    acc = __builtin_amdgcn_mfma_f32_16x16x32_bf16(a0, bfr2[0][nt], acc, 0, 0, 0);
                    acc = __builtin_amdgcn_mfma_f32_16x16x32_bf16(a1, bfr2[1][nt], acc, 0, 0, 0);
                    unsigned w0 = bfpair(acc[0], acc[1]);
                    unsigned w1 = bfpair(acc[2], acc[3]);
                    if (nt == 0) { st.x = w0; st.y = w1; } else { st.z = w0; st.w = w1; }
                }
                reinterpret_cast<uint4*>(ep2)[tix * 64 + lane] = st;
            }
            // ep3 -> packed D-frag blob
            {
                uint4 st;
                #pragma unroll
                for (int nt = 0; nt < 2; nt++) {
                    f32x4 acc = {0.f, 0.f, 0.f, 0.f};
                    acc = __builtin_amdgcn_mfma_f32_16x16x32_bf16(a0, bfr3[0][nt], acc, 0, 0, 0);
                    acc = __builtin_amdgcn_mfma_f32_16x16x32_bf16(a1, bfr3[1][nt], acc, 0, 0, 0);
                    unsigned w0 = bfpair(acc[0], acc[1]);
                    unsigned w1 = bfpair(acc[2], acc[3]);
                    if (nt == 0) { st.x = w0; st.y = w1; } else { st.z = w0; st.w = w1; }
                }
                reinterpret_cast<uint4*>(ep3)[tix * 64 + lane] = st;
            }
        }

        // ---- issue NEXT chunk's gathers (in flight across the reduce) ----
        float4 fn[2][4];
        if (ch < 3) {
            const int rbn = wv * 128 + (ch + 1) * 32;
            #pragma unroll
            for (int mt = 0; mt < 2; mt++) {
                const int eid = eidL[rbn + mt * 16 + lc];
                const float4* erow = reinterpret_cast<const float4*>(efeats + (long long)eid * 64);
                fn[mt][0] = erow[lg * 2];     fn[mt][1] = erow[lg * 2 + 1];
                fn[mt][2] = erow[8 + lg * 2]; fn[mt][3] = erow[8 + lg * 2 + 1];
            }
        }

        // ---- segmented reduce over this chunk's 32 rows (same-wave LDS) ----
        const int base = rb0;
        for (int r0 = 0; r0 < 32; ++r0) {
            int dr = dseg[base + r0];
            if (r0 > 0 && dseg[base + r0 - 1] == dr) continue;
            float s = 0.f;
            int rr = r0;
            while (true) {
                s += msgW[rr * MS + lane];
                ++rr;
                if (rr >= 32 || dseg[base + rr] != dr) break;
            }
            if (lane < FOUT) atomicAdd(agg + (long long)dr * FOUT + lane, s);
        }

        if (ch < 3) {
            #pragma unroll
            for (int mt = 0; mt < 2; mt++)
                #pragma unroll
                for (int q = 0; q < 4; q++) f[mt][q] = fn[mt][q];
        }
    }
}

// ===========================================================================
// Layers 2/3 edge kernel, SOFTWARE-PIPELINED: reads packed ep blob (one
// coalesced uint4/lane/tile) + gathered g[src]; next chunk's blob+g-values
// prefetched before the segmented reduce.
// ===========================================================================
template<int FOUT, int FOUTP>
__global__ __launch_bounds__(256) void edge_ep(
    const float* __restrict__ g,
    const unsigned* __restrict__ ep,     // [E/16][64] uint4 frag blobs
    const int4* __restrict__ recs,
    float* __restrict__ agg)
{
    constexpr int NT = 2;
    constexpr int MS = NT * 16 + 1;

    __shared__ float msg[4][32 * MS];
    __shared__ int sIdxL[512], dseg[512];

    const int tid = threadIdx.x;
    const long long pb = (long long)blockIdx.x * 512;
    {
        int4 r0 = recs[pb + tid];
        int4 r1 = recs[pb + 256 + tid];
        dseg[tid] = r0.y;  sIdxL[tid] = r0.z;
        dseg[tid + 256] = r1.y; sIdxL[tid + 256] = r1.z;
    }
    __syncthreads();

    const int lane = tid & 63;
    const int wv   = tid >> 6;
    const int lg   = lane >> 4;
    const int lc   = lane & 15;

    float* msgW = msg[wv];

    // prologue: load chunk 0's blobs + g-values
    uint4 v[2];
    float gv[2][2][4];
    {
        const int rb0 = wv * 128;
        #pragma unroll
        for (int mt = 0; mt < 2; mt++) {
            const long long tix = (pb >> 4) + wv * 8 + mt;
            v[mt] = reinterpret_cast<const uint4*>(ep)[tix * 64 + lane];
            #pragma unroll
            for (int nt = 0; nt < 2; nt++) {
                const int col = nt * 16 + lc;
                #pragma unroll
                for (int r = 0; r < 4; r++) {
                    int sr = sIdxL[rb0 + mt * 16 + lg * 4 + r];
                    gv[mt][nt][r] = (col < FOUT) ? g[(long long)sr * FOUTP + col] : 0.f;
                }
            }
        }
    }

    #pragma unroll 1
    for (int ch = 0; ch < 4; ++ch) {
        const int rb0 = wv * 128 + ch * 32;

        // ---- compute msg from prefetched v, gv ----
        #pragma unroll
        for (int mt = 0; mt < 2; mt++) {
            #pragma unroll
            for (int nt = 0; nt < 2; nt++) {
                unsigned w0 = (nt == 0) ? v[mt].x : v[mt].z;
                unsigned w1 = (nt == 0) ? v[mt].y : v[mt].w;
                float ev[4] = {bflo(w0), bfhi(w0), bflo(w1), bfhi(w1)};
                const int col = nt * 16 + lc;
                #pragma unroll
                for (int r = 0; r < 4; r++)
                    msgW[(mt * 16 + lg * 4 + r) * MS + col] = fmaxf(ev[r] + gv[mt][nt][r], 0.f);
            }
        }

        // ---- prefetch next chunk (in flight across the reduce) ----
        uint4 vn[2];
        float gvn[2][2][4];
        if (ch < 3) {
            const int rbn = wv * 128 + (ch + 1) * 32;
            #pragma unroll
            for (int mt = 0; mt < 2; mt++) {
                const long long tix = (pb >> 4) + wv * 8 + (ch + 1) * 2 + mt;
                vn[mt] = reinterpret_cast<const uint4*>(ep)[tix * 64 + lane];
                #pragma unroll
                for (int nt = 0; nt < 2; nt++) {
                    const int col = nt * 16 + lc;
                    #pragma unroll
                    for (int r = 0; r < 4; r++) {
                        int sr = sIdxL[rbn + mt * 16 + lg * 4 + r];
                        gvn[mt][nt][r] = (col < FOUT) ? g[(long long)sr * FOUTP + col] : 0.f;
                    }
                }
            }
        }

        // ---- segmented reduce ----
        const int base = rb0;
        for (int r0 = 0; r0 < 32; ++r0) {
            int dr = dseg[base + r0];
            if (r0 > 0 && dseg[base + r0 - 1] == dr) continue;
            float s = 0.f;
            int rr = r0;
            while (true) {
                if (lane < NT * 16) s += msgW[rr * MS + lane];
                ++rr;
                if (rr >= 32 || dseg[base + rr] != dr) break;
            }
            if (lane < FOUT) atomicAdd(agg + (long long)dr * FOUT + lane, s);
        }

        if (ch < 3) {
            #pragma unroll
            for (int mt = 0; mt < 2; mt++) {
                v[mt] = vn[mt];
                #pragma unroll
                for (int nt = 0; nt < 2; nt++)
                    #pragma unroll
                    for (int r = 0; r < 4; r++) gv[mt][nt][r] = gvn[mt][nt][r];
            }
        }
    }
}

// ===========================================================================
// FALLBACK edge kernel (ws too small for ep2/ep3): round-10 proven structure.
// ===========================================================================
template<int FOUT, int FOUTP, int MS>
__global__ __launch_bounds__(256) void edge_fb(
    const float* __restrict__ g,
    const float* __restrict__ efeats,
    const int4* __restrict__ recs,
    const float* __restrict__ Wp,
    float* __restrict__ agg)
{
    constexpr int F4 = FOUTP / 4;
    constexpr int ST = 17;
    static_assert(128 * MS + 64 <= 512 * ST, "msg buf exceeds sbuf");

    __shared__ float sbuf[512 * ST];
    __shared__ int   dseg[512];

    const int tid = threadIdx.x;
    const long long pb = (long long)blockIdx.x * 512;
    int4 r0 = recs[pb + tid];
    int4 r1 = recs[pb + 256 + tid];
    dseg[tid] = r0.y;
    dseg[tid + 256] = r1.y;

    const float4* gr0 = reinterpret_cast<const float4*>(g + (long long)r0.z * FOUTP);
    const float4* gr1 = reinterpret_cast<const float4*>(g + (long long)r1.z * FOUTP);
    const float*  er0 = efeats + (long long)r0.x * 64;
    const float*  er1 = efeats + (long long)r1.x * 64;
    const float4* Wp4 = reinterpret_cast<const float4*>(Wp);

    float4 acc0[F4], acc1[F4];
    #pragma unroll
    for (int j4 = 0; j4 < F4; j4++) acc0[j4] = gr0[j4];
    #pragma unroll
    for (int j4 = 0; j4 < F4; j4++) acc1[j4] = gr1[j4];

    const int t0 = tid * ST;
    const int t1 = (tid + 256) * ST;

    for (int c = 0; c < 4; ++c) {
        const int off = c * 16;
        #pragma unroll
        for (int f = 0; f < 4; ++f) {
            float4 v0 = *reinterpret_cast<const float4*>(er0 + off + 4 * f);
            float4 v1 = *reinterpret_cast<const float4*>(er1 + off + 4 * f);
            float* d0 = &sbuf[t0 + 4 * f];
            float* d1 = &sbuf[t1 + 4 * f];
            d0[0] = v0.x; d0[1] = v0.y; d0[2] = v0.z; d0[3] = v0.w;
            d1[0] = v1.x; d1[1] = v1.y; d1[2] = v1.z; d1[3] = v1.w;
        }
        #pragma unroll 1
        for (int k = 0; k < 16; ++k) {
            const float x0 = sbuf[t0 + k];
            const float x1 = sbuf[t1 + k];
            const float4* wrow = &Wp4[(off + k) * F4];
            #pragma unroll
            for (int j4 = 0; j4 < F4; j4++) {
                float4 w = wrow[j4];
                fma4(acc0[j4], w, x0);
                fma4(acc1[j4], w, x1);
            }
        }
    }

    const int lane = tid & 63;
    const int wv   = tid >> 6;

    #pragma unroll 1
    for (int bb = 0; bb < 4; ++bb) {
        __syncthreads();
        if ((tid >> 7) == (bb & 1)) {
            const int r = tid & 127;
            float* mrow = &sbuf[r * MS];
            const float4* accp = (bb < 2) ? acc0 : acc1;
            #pragma unroll
            for (int j4 = 0; j4 < F4; j4++) {
                float4 a = accp[j4];
                if (4 * j4 + 0 < FOUT) mrow[4 * j4 + 0] = fmaxf(a.x, 0.f);
                if (4 * j4 + 1 < FOUT) mrow[4 * j4 + 1] = fmaxf(a.y, 0.f);
                if (4 * j4 + 2 < FOUT) mrow[4 * j4 + 2] = fmaxf(a.z, 0.f);
                if (4 * j4 + 3 < FOUT) mrow[4 * j4 + 3] = fmaxf(a.w, 0.f);
            }
        }
        __syncthreads();

        const int rbase = bb * 128;
        for (int r0i = wv * 32; r0i < wv * 32 + 32; ++r0i) {
            int dr = dseg[rbase + r0i];
            if (r0i > 0 && dseg[rbase + r0i - 1] == dr) continue;
            float s = 0.f;
            int rr = r0i;
            while (true) {
                s += sbuf[rr * MS + lane];
                ++rr;
                if (rr >= 128 || dseg[rbase + rr] != dr) break;
            }
            if (lane < FOUT) atomicAdd(agg + (long long)dr * FOUT + lane, s);
        }
    }
}

// ===========================================================================
// Node kernel (fused): h_next = relu(cat(h, agg) @ Wa + ba), plus fused
// g_next = h_next @ Wm_next(h-part) + bm_next when GOUT > 0.
// ===========================================================================
template<int FH, int FHP, int FAGG, int FOUT, int FOUTP, int GOUT, int GOUTP>
__global__ __launch_bounds__(256) void node_kernel(
    const float* __restrict__ h,
    const float* __restrict__ agg,
    const float* __restrict__ Wa,
    const float* __restrict__ ba,
    const float* __restrict__ Wmn,
    const float* __restrict__ bmn,
    float* __restrict__ out,
    float* __restrict__ gout,
    int nNodes)
{
    constexpr int K  = FH + FAGG;
    constexpr int F4 = FOUTP / 4;
    constexpr int G4 = (GOUT > 0) ? GOUTP / 4 : 1;

    __shared__ float4 Wl[K * F4];
    __shared__ float4 Wg[(GOUT > 0) ? FOUTP * G4 : 1];
    __shared__ float  bl[FOUTP];
    __shared__ float  bg[(GOUT > 0) ? GOUTP : 4];

    const int tid = threadIdx.x;
    for (int idx = tid; idx < K * FOUTP; idx += 256) {
        int k = idx / FOUTP, j = idx - k * FOUTP;
        reinterpret_cast<float*>(Wl)[idx] = (j < FOUT) ? Wa[k * FOUT + j] : 0.f;
    }
    for (int idx = tid; idx < FOUTP; idx += 256)
        bl[idx] = (idx < FOUT) ? ba[idx] : 0.f;
    if constexpr (GOUT > 0) {
        for (int idx = tid; idx < FOUTP * GOUTP; idx += 256) {
            int k = idx / GOUTP, j = idx - k * GOUTP;
            reinterpret_cast<float*>(Wg)[idx] =
                (k < FOUT && j < GOUT) ? Wmn[k * GOUT + j] : 0.f;
        }
        for (int idx = tid; idx < GOUTP; idx += 256)
            bg[idx] = (idx < GOUT) ? bmn[idx] : 0.f;
    }
    __syncthreads();

    const int n = blockIdx.x * 256 + tid;
    if (n >= nNodes) return;

    float4 acc[F4];
    #pragma unroll
    for (int j4 = 0; j4 < F4; j4++) acc[j4] = reinterpret_cast<float4*>(bl)[j4];

    const float* hrow = h + (long long)n * FHP;
    #pragma unroll 1
    for (int k = 0; k < FH; k++) {
        float xk = hrow[k];
        const float4* wrow = &Wl[k * F4];
        #pragma unroll
        for (int j4 = 0; j4 < F4; j4++) fma4(acc[j4], wrow[j4], xk);
    }
    const float* arow = agg + (long long)n * FAGG;
    #pragma unroll 1
    for (int k = 0; k < FAGG; k++) {
        float xk = arow[k];
        const float4* wrow = &Wl[(FH + k) * F4];
        #pragma unroll
        for (int j4 = 0; j4 < F4; j4++) fma4(acc[j4], wrow[j4], xk);
    }

    #pragma unroll
    for (int j4 = 0; j4 < F4; j4++) {
        acc[j4].x = fmaxf(acc[j4].x, 0.f);
        acc[j4].y = fmaxf(acc[j4].y, 0.f);
        acc[j4].z = fmaxf(acc[j4].z, 0.f);
        acc[j4].w = fmaxf(acc[j4].w, 0.f);
    }
    float4* orow = reinterpret_cast<float4*>(out + (long long)n * FOUTP);
    #pragma unroll
    for (int j4 = 0; j4 < F4; j4++) orow[j4] = acc[j4];

    if constexpr (GOUT > 0) {
        float4 gacc[G4];
        #pragma unroll
        for (int j4 = 0; j4 < G4; j4++) gacc[j4] = reinterpret_cast<float4*>(bg)[j4];
        #pragma unroll 1
        for (int k4 = 0; k4 < F4; ++k4) {
            float4 xv = acc[k4];
            #pragma unroll
            for (int c = 0; c < 4; ++c) {
                float xc = (c == 0) ? xv.x : (c == 1) ? xv.y : (c == 2) ? xv.z : xv.w;
                const float4* wrow = &Wg[(k4 * 4 + c) * G4];
                #pragma unroll
                for (int j4 = 0; j4 < G4; j4++) fma4(gacc[j4], wrow[j4], xc);
            }
        }
        float4* grow = reinterpret_cast<float4*>(gout + (long long)n * GOUTP);
        #pragma unroll
        for (int j4 = 0; j4 < G4; j4++) grow[j4] = gacc[j4];
    }
}

extern "C" void kernel_launch(void* const* d_in, const int* in_sizes, int n_in,
                              void* d_out, int out_size, void* d_ws, size_t ws_size,
                              hipStream_t stream)
{
    const float* nfeats = (const float*)d_in[0];
    const float* efeats = (const float*)d_in[1];
    const int*   src    = (const int*)d_in[2];
    const int*   dst    = (const int*)d_in[3];
    const float* Wm1 = (const float*)d_in[4],  *bm1 = (const float*)d_in[5];
    const float* Wa1 = (const float*)d_in[6],  *ba1 = (const float*)d_in[7];
    const float* Wm2 = (const float*)d_in[8],  *bm2 = (const float*)d_in[9];
    const float* Wa2 = (const float*)d_in[10], *ba2 = (const float*)d_in[11];
    const float* Wm3 = (const float*)d_in[12], *bm3 = (const float*)d_in[13];
    const float* Wa3 = (const float*)d_in[14], *ba3 = (const float*)d_in[15];
    float* out = (float*)d_out;

    constexpr int N = 100000;
    constexpr int E = 3200000;                      // % 512 == 0
    constexpr int SCAN_BLOCKS = (N + 1023) / 1024;  // 98

    float* ws   = (float*)d_ws;
    float* h1   = ws;                            // N x 52
    float* h2   = h1 + (size_t)N * 52;           // N x 28
    float* agg  = h2 + (size_t)N * 28;           // N x 52
    float* g    = agg + (size_t)N * 52;          // N x 52
    int* counts = (int*)(g + (size_t)N * 52);    // N
    int* cursor = counts + N;                    // N
    int* bsums  = cursor + N;                    // 128
    int4* recs  = (int4*)(bsums + 128);          // E x 16B
    float* Wp1  = (float*)(recs + E);            // 64 x 52 fp32 (fallback)
    float* Wp2  = Wp1 + 64 * 52;                 // 64 x 28
    float* Wp3  = Wp2 + 64 * 28;                 // 64 x 32
    unsigned short* Wb1 = (unsigned short*)(Wp3 + 64 * 32); // 64 x 64 bf16
    unsigned short* Wb2 = Wb1 + 64 * 64;                    // 32 x 64 bf16
    unsigned short* Wb3 = Wb2 + 32 * 64;                    // 32 x 64 bf16
    char* endp = (char*)(Wb3 + 32 * 64);

    size_t usedB  = (size_t)(endp - (char*)d_ws);
    size_t epOffB = (usedB + 127) & ~(size_t)127;
    size_t neededB = epOffB + (size_t)E * 128;   // ep2 (E x 64B) + ep3 (E x 64B)
    const bool useBf = (ws_size >= neededB);
    unsigned* ep2 = (unsigned*)((char*)d_ws + epOffB);
    unsigned* ep3 = ep2 + (size_t)E * 16;        // E x 16 u32 = E x 64B

    // ---- pack W tables ----
    pack_we<64, 50, 52><<<(64 * 52 + 255) / 256, 256, 0, stream>>>(Wm1, Wp1);
    pack_we<50, 25, 28><<<(64 * 28 + 255) / 256, 256, 0, stream>>>(Wm2, Wp2);
    pack_we<25, 32, 32><<<(64 * 32 + 255) / 256, 256, 0, stream>>>(Wm3, Wp3);
    pack_wbt<64, 50, 64><<<(64 * 64 + 255) / 256, 256, 0, stream>>>(Wm1, Wb1);
    pack_wbt<50, 25, 32><<<(32 * 64 + 255) / 256, 256, 0, stream>>>(Wm2, Wb2);
    pack_wbt<25, 32, 32><<<(32 * 64 + 255) / 256, 256, 0, stream>>>(Wm3, Wb3);

    // ---- CSR build (counting sort by dst; payload = int4 record) ----
    hipMemsetAsync(counts, 0, (size_t)N * sizeof(int), stream);
    hist_kernel<<<2048, 256, 0, stream>>>(dst, counts, E);
    scan_block<<<SCAN_BLOCKS, 1024, 0, stream>>>(counts, cursor, bsums, N);
    scan_small<<<1, 64, 0, stream>>>(bsums, SCAN_BLOCKS);
    add_offsets<<<SCAN_BLOCKS, 1024, 0, stream>>>(cursor, bsums, N);
    scatter_kernel<<<2048, 256, 0, stream>>>(dst, src, cursor, recs, E);

    const int EB = E / 512;
    const int NB = (N + 255) / 256;

    // ---- g1 = nfeats @ Wm1(h-part) + bm1 ----
    gemv_g<64, 50, 52><<<NB, 256, 0, stream>>>(nfeats, Wm1, bm1, g, N);

    // ---- layer 1 (computes ep2/ep3 for layers 2/3 in the same pass) ----
    hipMemsetAsync(agg, 0, (size_t)N * 52 * sizeof(float), stream);
    if (useBf)
        edge_mfma_all<<<EB, 256, 0, stream>>>(g, efeats, recs, Wb1, Wb2, Wb3, ep2, ep3, agg);
    else
        edge_fb<50, 52, 51><<<EB, 256, 0, stream>>>(g, efeats, recs, Wp1, agg);
    node_kernel<64, 64, 50, 50, 52, 25, 28><<<NB, 256, 0, stream>>>(
        nfeats, agg, Wa1, ba1, Wm2, bm2, h1, g, N);

    // ---- layer 2 (pure stream + gather + reduce) ----
    hipMemsetAsync(agg, 0, (size_t)N * 52 * sizeof(float), stream);
    if (useBf)
        edge_ep<25, 28><<<EB, 256, 0, stream>>>(g, ep2, recs, agg);
    else
        edge_fb<25, 28, 25><<<EB, 256, 0, stream>>>(g, efeats, recs, Wp2, agg);
    node_kernel<50, 52, 25, 25, 28, 32, 32><<<NB, 256, 0, stream>>>(
        h1, agg, Wa2, ba2, Wm3, bm3, h2, g, N);

    // ---- layer 3 ----
    hipMemsetAsync(agg, 0, (size_t)N * 52 * sizeof(float), stream);
    if (useBf)
        edge_ep<32, 32><<<EB, 256, 0, stream>>>(g, ep3, recs, agg);
    else
        edge_fb<32, 32, 33><<<EB, 256, 0, stream>>>(g, efeats, recs, Wp3, agg);
    node_kernel<25, 28, 32, 32, 32, 0, 0><<<NB, 256, 0, stream>>>(
        h2, agg, Wa3, ba3, nullptr, nullptr, out, nullptr, N);
}

// Round 15
// 1299.296 us; speedup vs baseline: 1.1941x; 1.0758x over previous
//
#include <hip/hip_runtime.h>

#define DEVINL __device__ __forceinline__

typedef __attribute__((ext_vector_type(8))) short bf16x8;
typedef __attribute__((ext_vector_type(4))) float f32x4;

DEVINL void fma4(float4& a, const float4 w, const float x) {
    a.x += w.x * x; a.y += w.y * x; a.z += w.z * x; a.w += w.w * x;
}

DEVINL unsigned short bf16of(float x) {
    unsigned a = __float_as_uint(x);
    a += 0x7FFFu + ((a >> 16) & 1u);
    return (unsigned short)(a >> 16);
}

// pack two fp32 into one u32 of 2 bf16 (RNE); element "lo" in low half
DEVINL unsigned bfpair(float lo, float hi) {
    unsigned a = __float_as_uint(lo);
    a += 0x7FFFu + ((a >> 16) & 1u);
    unsigned b = __float_as_uint(hi);
    b += 0x7FFFu + ((b >> 16) & 1u);
    return (a >> 16) | (b & 0xFFFF0000u);
}

DEVINL bf16x8 as_bf16x8(uint4 u) {
    union { uint4 u4; bf16x8 b; } cv; cv.u4 = u; return cv.b;
}

// ===========================================================================
// CSR build: counting sort of edges by dst.
// ===========================================================================
__global__ __launch_bounds__(256) void hist_kernel(const int* __restrict__ d,
                                                   int* __restrict__ counts, int n) {
    for (int i = blockIdx.x * 256 + threadIdx.x; i < n; i += gridDim.x * 256)
        atomicAdd(&counts[d[i]], 1);
}

__global__ __launch_bounds__(1024) void scan_block(const int* __restrict__ in,
                                                   int* __restrict__ out,
                                                   int* __restrict__ bsums, int n) {
    __shared__ int buf[2][1024];
    const int t = threadIdx.x;
    const int i = blockIdx.x * 1024 + t;
    const int v = (i < n) ? in[i] : 0;
    int cur = 0;
    buf[0][t] = v;
    __syncthreads();
    #pragma unroll
    for (int s = 1; s < 1024; s <<= 1) {
        int x = buf[cur][t];
        if (t >= s) x += buf[cur][t - s];
        buf[cur ^ 1][t] = x;
        cur ^= 1;
        __syncthreads();
    }
    if (i < n) out[i] = buf[cur][t] - v;            // exclusive
    if (t == 1023) bsums[blockIdx.x] = buf[cur][t]; // block total
}

__global__ void scan_small(int* __restrict__ bs, int nb) {
    if (blockIdx.x == 0 && threadIdx.x == 0) {
        int acc = 0;
        for (int i = 0; i < nb; i++) { int v = bs[i]; bs[i] = acc; acc += v; }
    }
}

__global__ __launch_bounds__(1024) void add_offsets(int* __restrict__ out,
                                                    const int* __restrict__ bs, int n) {
    int i = blockIdx.x * 1024 + threadIdx.x;
    if (i < n) out[i] += bs[blockIdx.x];
}

// ===========================================================================
// cvt_scatter: fused CSR-scatter + bf16 convert. 4 lanes per edge.
//   - reads dst/src/efeats SEQUENTIALLY (full-BW stream)
//   - lane sub==0 claims sorted position pos (atomic) and writes the int4
//     record {eid, dst, src, 0}; pos broadcast to the 4-lane group via shfl
//   - the group converts its 256B fp32 row to bf16 and writes the 128B row
//     at ebf[pos] (random WRITE: fire-and-forget, does not stall the wave —
//     this moves the edge-permutation randomness off the read-critical path)
// Grid sized exactly: nEdges % 64 == 0 (64 edges per 256-thread block).
// ===========================================================================
__global__ __launch_bounds__(256) void cvt_scatter(
    const int* __restrict__ dst,
    const int* __restrict__ src,
    const float* __restrict__ ef,
    int* __restrict__ cursor,
    int4* __restrict__ recs,
    unsigned* __restrict__ ebf)   // may be nullptr (fallback path)
{
    const int tid = threadIdx.x;
    const long long e = (long long)blockIdx.x * 64 + (tid >> 2);
    const int sub  = tid & 3;
    const int lane = tid & 63;

    const int dd = dst[e];
    const int ss = src[e];
    int pos = 0;
    if (sub == 0) pos = atomicAdd(&cursor[dd], 1);
    pos = __shfl(pos, lane & ~3);      // broadcast within the 4-lane group
    if (sub == 0) recs[pos] = make_int4((int)e, dd, ss, 0);

    if (ebf != nullptr) {
        const float4* erow = reinterpret_cast<const float4*>(ef + e * 64);
        float4 q0 = erow[sub * 4 + 0];
        float4 q1 = erow[sub * 4 + 1];
        float4 q2 = erow[sub * 4 + 2];
        float4 q3 = erow[sub * 4 + 3];
        uint4 o0, o1;
        o0.x = bfpair(q0.x, q0.y); o0.y = bfpair(q0.z, q0.w);
        o0.z = bfpair(q1.x, q1.y); o0.w = bfpair(q1.z, q1.w);
        o1.x = bfpair(q2.x, q2.y); o1.y = bfpair(q2.z, q2.w);
        o1.z = bfpair(q3.x, q3.y); o1.w = bfpair(q3.z, q3.w);
        uint4* outp = reinterpret_cast<uint4*>(ebf + (long long)pos * 32);
        outp[sub * 2]     = o0;
        outp[sub * 2 + 1] = o1;
    }
}

// ===========================================================================
// pack_we (fp32, fallback path): e-part rows -> padded [64][FOUTP].
// ===========================================================================
template<int FIN, int FOUT, int FOUTP>
__global__ __launch_bounds__(256) void pack_we(const float* __restrict__ W,
                                               float* __restrict__ Wp) {
    int idx = blockIdx.x * 256 + threadIdx.x;
    if (idx >= 64 * FOUTP) return;
    int k = idx / FOUTP, j = idx - k * FOUTP;
    Wp[idx] = (j < FOUT) ? W[(FIN + k) * FOUT + j] : 0.f;
}

// ===========================================================================
// pack_wbt: e-part of Wm -> bf16 TRANSPOSED table WbT[col][64].
// ===========================================================================
template<int FIN, int FOUT, int NC>
__global__ __launch_bounds__(256) void pack_wbt(const float* __restrict__ W,
                                                unsigned short* __restrict__ WbT) {
    int idx = blockIdx.x * 256 + threadIdx.x;
    if (idx >= NC * 64) return;
    int c = idx / 64, k = idx - c * 64;
    WbT[idx] = (c < FOUT) ? bf16of(W[(FIN + k) * FOUT + c]) : (unsigned short)0;
}

// ===========================================================================
// gemv_g: g = x @ W(h-part rows [0,FIN)) + b, padded to FOUTP.
// ===========================================================================
template<int FIN, int FOUT, int FOUTP>
__global__ __launch_bounds__(256) void gemv_g(
    const float* __restrict__ x,
    const float* __restrict__ W,
    const float* __restrict__ b,
    float* __restrict__ g, int nNodes)
{
    constexpr int F4 = FOUTP / 4;
    __shared__ float4 Wl[FIN * F4];
    __shared__ float  bl[FOUTP];
    const int tid = threadIdx.x;
    for (int idx = tid; idx < FIN * FOUTP; idx += 256) {
        int k = idx / FOUTP, j = idx - k * FOUTP;
        reinterpret_cast<float*>(Wl)[idx] = (j < FOUT) ? W[k * FOUT + j] : 0.f;
    }
    for (int idx = tid; idx < FOUTP; idx += 256)
        bl[idx] = (idx < FOUT) ? b[idx] : 0.f;
    __syncthreads();
    const int n = blockIdx.x * 256 + tid;
    if (n >= nNodes) return;
    float4 acc[F4];
    #pragma unroll
    for (int j4 = 0; j4 < F4; j4++) acc[j4] = reinterpret_cast<float4*>(bl)[j4];
    const float* xr = x + (long long)n * FIN;
    #pragma unroll 1
    for (int k = 0; k < FIN; ++k) {
        float xk = xr[k];
        const float4* wrow = &Wl[k * F4];
        #pragma unroll
        for (int j4 = 0; j4 < F4; j4++) fma4(acc[j4], wrow[j4], xk);
    }
    float4* gr = reinterpret_cast<float4*>(g + (long long)n * FOUTP);
    #pragma unroll
    for (int j4 = 0; j4 < F4; j4++) gr[j4] = acc[j4];
}

// ===========================================================================
// Unified edge kernel (all layers): m = relu(g[src] + e @ We).
//   A-frags stream SEQUENTIALLY from the sorted bf16 ebf (16B/lane loads);
//   B (We bf16^T) lives in 8/4 frags of VGPRs; g-values prefetched before
//   the MFMA cluster; next chunk's A-frags prefetched across the segmented
//   reduce (r14's pipeline). Epilogue: wave-private msg tile + segmented
//   reduce by sorted dst, ~1 atomic per (segment, feature). No main-loop
//   barriers. MFMA frag semantics HW-verified r11:
//   A lane: row=l&15, k=(l>>4)*8+j; B lane: col=l&15; D: col=l&15,
//   row=(l>>4)*4+reg.
// ===========================================================================
template<int FOUT, int FOUTP, int NT>
__global__ __launch_bounds__(256) void edge_mfma(
    const float* __restrict__ g,
    const unsigned* __restrict__ ebf,      // [E][32] u32, sorted order
    const int4* __restrict__ recs,         // sorted {eid,dst,src,0}
    const unsigned short* __restrict__ WbT,
    float* __restrict__ agg)
{
    constexpr int MS = NT * 16 + 1;

    __shared__ float msg[4][32 * MS];
    __shared__ int sIdxL[512], dseg[512];

    const int tid = threadIdx.x;
    const long long pb = (long long)blockIdx.x * 512;
    {
        int4 r0 = recs[pb + tid];
        int4 r1 = recs[pb + 256 + tid];
        dseg[tid] = r0.y;  sIdxL[tid] = r0.z;
        dseg[tid + 256] = r1.y; sIdxL[tid + 256] = r1.z;
    }
    __syncthreads();

    const int lane = tid & 63;
    const int wv   = tid >> 6;
    const int lg   = lane >> 4;
    const int lc   = lane & 15;

    bf16x8 bfr[2][NT];
    #pragma unroll
    for (int kt = 0; kt < 2; kt++)
        #pragma unroll
        for (int nt = 0; nt < NT; nt++)
            bfr[kt][nt] = *reinterpret_cast<const bf16x8*>(
                WbT + (nt * 16 + lc) * 64 + kt * 32 + lg * 8);

    float* msgW = msg[wv];

    // prologue: chunk 0 A-frags (sequential 16B/lane loads)
    bf16x8 a0[2], a1[2];
    #pragma unroll
    for (int mt = 0; mt < 2; mt++) {
        const unsigned* arow = ebf + (unsigned long long)(pb + wv * 128 + mt * 16 + lc) * 32;
        a0[mt] = *reinterpret_cast<const bf16x8*>(arow + lg * 4);
        a1[mt] = *reinterpret_cast<const bf16x8*>(arow + 16 + lg * 4);
    }

    #pragma unroll 1
    for (int ch = 0; ch < 4; ++ch) {
        const int rb0 = wv * 128 + ch * 32;

        // ---- prefetch epilogue g-values (overlaps the MFMA cluster) ----
        int srr[2][4];
        #pragma unroll
        for (int mt = 0; mt < 2; mt++)
            #pragma unroll
            for (int r = 0; r < 4; r++)
                srr[mt][r] = sIdxL[rb0 + mt * 16 + lg * 4 + r];
        float gv[2][NT][4];
        #pragma unroll
        for (int mt = 0; mt < 2; mt++)
            #pragma unroll
            for (int nt = 0; nt < NT; nt++) {
                const int col = nt * 16 + lc;
                #pragma unroll
                for (int r = 0; r < 4; r++)
                    gv[mt][nt][r] = (col < FOUT) ? g[(long long)srr[mt][r] * FOUTP + col] : 0.f;
            }

        // ---- compute both tiles ----
        #pragma unroll
        for (int mt = 0; mt < 2; mt++) {
            #pragma unroll
            for (int nt = 0; nt < NT; nt++) {
                f32x4 acc = {0.f, 0.f, 0.f, 0.f};
                acc = __builtin_amdgcn_mfma_f32_16x16x32_bf16(a0[mt], bfr[0][nt], acc, 0, 0, 0);
                acc = __builtin_amdgcn_mfma_f32_16x16x32_bf16(a1[mt], bfr[1][nt], acc, 0, 0, 0);
                const int col = nt * 16 + lc;
                #pragma unroll
                for (int r = 0; r < 4; r++)
                    msgW[(mt * 16 + lg * 4 + r) * MS + col] = fmaxf(acc[r] + gv[mt][nt][r], 0.f);
            }
        }

        // ---- prefetch next chunk's A-frags (in flight across the reduce) ----
        bf16x8 n0[2], n1[2];
        if (ch < 3) {
            const int rbn = wv * 128 + (ch + 1) * 32;
            #pragma unroll
            for (int mt = 0; mt < 2; mt++) {
                const unsigned* arow = ebf + (unsigned long long)(pb + rbn + mt * 16 + lc) * 32;
                n0[mt] = *reinterpret_cast<const bf16x8*>(arow + lg * 4);
                n1[mt] = *reinterpret_cast<const bf16x8*>(arow + 16 + lg * 4);
            }
        }

        // ---- segmented reduce over this chunk's 32 rows (same-wave LDS) ----
        const int base = rb0;
        for (int r0 = 0; r0 < 32; ++r0) {
            int dr = dseg[base + r0];
            if (r0 > 0 && dseg[base + r0 - 1] == dr) continue;
            float s = 0.f;
            int rr = r0;
            while (true) {
                if (lane < NT * 16) s += msgW[rr * MS + lane];
                ++rr;
                if (rr >= 32 || dseg[base + rr] != dr) break;
            }
            if (lane < FOUT) atomicAdd(agg + (long long)dr * FOUT + lane, s);
        }

        if (ch < 3) {
            #pragma unroll
            for (int mt = 0; mt < 2; mt++) { a0[mt] = n0[mt]; a1[mt] = n1[mt]; }
        }
    }
}

// ===========================================================================
// FALLBACK edge kernel (ws too small for ebf): round-10 proven structure.
// ===========================================================================
template<int FOUT, int FOUTP, int MS>
__global__ __launch_bounds__(256) void edge_fb(
    const float* __restrict__ g,
    const float* __restrict__ efeats,
    const int4* __restrict__ recs,
    const float* __restrict__ Wp,
    float* __restrict__ agg)
{
    constexpr int F4 = FOUTP / 4;
    constexpr int ST = 17;
    static_assert(128 * MS + 64 <= 512 * ST, "msg buf exceeds sbuf");

    __shared__ float sbuf[512 * ST];
    __shared__ int   dseg[512];

    const int tid = threadIdx.x;
    const long long pb = (long long)blockIdx.x * 512;
    int4 r0 = recs[pb + tid];
    int4 r1 = recs[pb + 256 + tid];
    dseg[tid] = r0.y;
    dseg[tid + 256] = r1.y;

    const float4* gr0 = reinterpret_cast<const float4*>(g + (long long)r0.z * FOUTP);
    const float4* gr1 = reinterpret_cast<const float4*>(g + (long long)r1.z * FOUTP);
    const float*  er0 = efeats + (long long)r0.x * 64;
    const float*  er1 = efeats + (long long)r1.x * 64;
    const float4* Wp4 = reinterpret_cast<const float4*>(Wp);

    float4 acc0[F4], acc1[F4];
    #pragma unroll
    for (int j4 = 0; j4 < F4; j4++) acc0[j4] = gr0[j4];
    #pragma unroll
    for (int j4 = 0; j4 < F4; j4++) acc1[j4] = gr1[j4];

    const int t0 = tid * ST;
    const int t1 = (tid + 256) * ST;

    for (int c = 0; c < 4; ++c) {
        const int off = c * 16;
        #pragma unroll
        for (int f = 0; f < 4; ++f) {
            float4 v0 = *reinterpret_cast<const float4*>(er0 + off + 4 * f);
            float4 v1 = *reinterpret_cast<const float4*>(er1 + off + 4 * f);
            float* d0 = &sbuf[t0 + 4 * f];
            float* d1 = &sbuf[t1 + 4 * f];
            d0[0] = v0.x; d0[1] = v0.y; d0[2] = v0.z; d0[3] = v0.w;
            d1[0] = v1.x; d1[1] = v1.y; d1[2] = v1.z; d1[3] = v1.w;
        }
        #pragma unroll 1
        for (int k = 0; k < 16; ++k) {
            const float x0 = sbuf[t0 + k];
            const float x1 = sbuf[t1 + k];
            const float4* wrow = &Wp4[(off + k) * F4];
            #pragma unroll
            for (int j4 = 0; j4 < F4; j4++) {
                float4 w = wrow[j4];
                fma4(acc0[j4], w, x0);
                fma4(acc1[j4], w, x1);
            }
        }
    }

    const int lane = tid & 63;
    const int wv   = tid >> 6;

    #pragma unroll 1
    for (int bb = 0; bb < 4; ++bb) {
        __syncthreads();
        if ((tid >> 7) == (bb & 1)) {
            const int r = tid & 127;
            float* mrow = &sbuf[r * MS];
            const float4* accp = (bb < 2) ? acc0 : acc1;
            #pragma unroll
            for (int j4 = 0; j4 < F4; j4++) {
                float4 a = accp[j4];
                if (4 * j4 + 0 < FOUT) mrow[4 * j4 + 0] = fmaxf(a.x, 0.f);
                if (4 * j4 + 1 < FOUT) mrow[4 * j4 + 1] = fmaxf(a.y, 0.f);
                if (4 * j4 + 2 < FOUT) mrow[4 * j4 + 2] = fmaxf(a.z, 0.f);
                if (4 * j4 + 3 < FOUT) mrow[4 * j4 + 3] = fmaxf(a.w, 0.f);
            }
        }
        __syncthreads();

        const int rbase = bb * 128;
        for (int r0i = wv * 32; r0i < wv * 32 + 32; ++r0i) {
            int dr = dseg[rbase + r0i];
            if (r0i > 0 && dseg[rbase + r0i - 1] == dr) continue;
            float s = 0.f;
            int rr = r0i;
            while (true) {
                s += sbuf[rr * MS + lane];
                ++rr;
                if (rr >= 128 || dseg[rbase + rr] != dr) break;
            }
            if (lane < FOUT) atomicAdd(agg + (long long)dr * FOUT + lane, s);
        }
    }
}

// ===========================================================================
// Node kernel (fused): h_next = relu(cat(h, agg) @ Wa + ba), plus fused
// g_next = h_next @ Wm_next(h-part) + bm_next when GOUT > 0.
// ===========================================================================
template<int FH, int FHP, int FAGG, int FOUT, int FOUTP, int GOUT, int GOUTP>
__global__ __launch_bounds__(256) void node_kernel(
    const float* __restrict__ h,
    const float* __restrict__ agg,
    const float* __restrict__ Wa,
    const float* __restrict__ ba,
    const float* __restrict__ Wmn,
    const float* __restrict__ bmn,
    float* __restrict__ out,
    float* __restrict__ gout,
    int nNodes)
{
    constexpr int K  = FH + FAGG;
    constexpr int F4 = FOUTP / 4;
    constexpr int G4 = (GOUT > 0) ? GOUTP / 4 : 1;

    __shared__ float4 Wl[K * F4];
    __shared__ float4 Wg[(GOUT > 0) ? FOUTP * G4 : 1];
    __shared__ float  bl[FOUTP];
    __shared__ float  bg[(GOUT > 0) ? GOUTP : 4];

    const int tid = threadIdx.x;
    for (int idx = tid; idx < K * FOUTP; idx += 256) {
        int k = idx / FOUTP, j = idx - k * FOUTP;
        reinterpret_cast<float*>(Wl)[idx] = (j < FOUT) ? Wa[k * FOUT + j] : 0.f;
    }
    for (int idx = tid; idx < FOUTP; idx += 256)
        bl[idx] = (idx < FOUT) ? ba[idx] : 0.f;
    if constexpr (GOUT > 0) {
        for (int idx = tid; idx < FOUTP * GOUTP; idx += 256) {
            int k = idx / GOUTP, j = idx - k * GOUTP;
            reinterpret_cast<float*>(Wg)[idx] =
                (k < FOUT && j < GOUT) ? Wmn[k * GOUT + j] : 0.f;
        }
        for (int idx = tid; idx < GOUTP; idx += 256)
            bg[idx] = (idx < GOUT) ? bmn[idx] : 0.f;
    }
    __syncthreads();

    const int n = blockIdx.x * 256 + tid;
    if (n >= nNodes) return;

    float4 acc[F4];
    #pragma unroll
    for (int j4 = 0; j4 < F4; j4++) acc[j4] = reinterpret_cast<float4*>(bl)[j4];

    const float* hrow = h + (long long)n * FHP;
    #pragma unroll 1
    for (int k = 0; k < FH; k++) {
        float xk = hrow[k];
        const float4* wrow = &Wl[k * F4];
        #pragma unroll
        for (int j4 = 0; j4 < F4; j4++) fma4(acc[j4], wrow[j4], xk);
    }
    const float* arow = agg + (long long)n * FAGG;
    #pragma unroll 1
    for (int k = 0; k < FAGG; k++) {
        float xk = arow[k];
        const float4* wrow = &Wl[(FH + k) * F4];
        #pragma unroll
        for (int j4 = 0; j4 < F4; j4++) fma4(acc[j4], wrow[j4], xk);
    }

    #pragma unroll
    for (int j4 = 0; j4 < F4; j4++) {
        acc[j4].x = fmaxf(acc[j4].x, 0.f);
        acc[j4].y = fmaxf(acc[j4].y, 0.f);
        acc[j4].z = fmaxf(acc[j4].z, 0.f);
        acc[j4].w = fmaxf(acc[j4].w, 0.f);
    }
    float4* orow = reinterpret_cast<float4*>(out + (long long)n * FOUTP);
    #pragma unroll
    for (int j4 = 0; j4 < F4; j4++) orow[j4] = acc[j4];

    if constexpr (GOUT > 0) {
        float4 gacc[G4];
        #pragma unroll
        for (int j4 = 0; j4 < G4; j4++) gacc[j4] = reinterpret_cast<float4*>(bg)[j4];
        #pragma unroll 1
        for (int k4 = 0; k4 < F4; ++k4) {
            float4 xv = acc[k4];
            #pragma unroll
            for (int c = 0; c < 4; ++c) {
                float xc = (c == 0) ? xv.x : (c == 1) ? xv.y : (c == 2) ? xv.z : xv.w;
                const float4* wrow = &Wg[(k4 * 4 + c) * G4];
                #pragma unroll
                for (int j4 = 0; j4 < G4; j4++) fma4(gacc[j4], wrow[j4], xc);
            }
        }
        float4* grow = reinterpret_cast<float4*>(gout + (long long)n * GOUTP);
        #pragma unroll
        for (int j4 = 0; j4 < G4; j4++) grow[j4] = gacc[j4];
    }
}

extern "C" void kernel_launch(void* const* d_in, const int* in_sizes, int n_in,
                              void* d_out, int out_size, void* d_ws, size_t ws_size,
                              hipStream_t stream)
{
    const float* nfeats = (const float*)d_in[0];
    const float* efeats = (const float*)d_in[1];
    const int*   src    = (const int*)d_in[2];
    const int*   dst    = (const int*)d_in[3];
    const float* Wm1 = (const float*)d_in[4],  *bm1 = (const float*)d_in[5];
    const float* Wa1 = (const float*)d_in[6],  *ba1 = (const float*)d_in[7];
    const float* Wm2 = (const float*)d_in[8],  *bm2 = (const float*)d_in[9];
    const float* Wa2 = (const float*)d_in[10], *ba2 = (const float*)d_in[11];
    const float* Wm3 = (const float*)d_in[12], *bm3 = (const float*)d_in[13];
    const float* Wa3 = (const float*)d_in[14], *ba3 = (const float*)d_in[15];
    float* out = (float*)d_out;

    constexpr int N = 100000;
    constexpr int E = 3200000;                      // % 512 == 0, % 64 == 0
    constexpr int SCAN_BLOCKS = (N + 1023) / 1024;  // 98

    float* ws   = (float*)d_ws;
    float* h1   = ws;                            // N x 52
    float* h2   = h1 + (size_t)N * 52;           // N x 28
    float* agg  = h2 + (size_t)N * 28;           // N x 52
    float* g    = agg + (size_t)N * 52;          // N x 52
    int* counts = (int*)(g + (size_t)N * 52);    // N
    int* cursor = counts + N;                    // N
    int* bsums  = cursor + N;                    // 128
    int4* recs  = (int4*)(bsums + 128);          // E x 16B
    float* Wp1  = (float*)(recs + E);            // 64 x 52 fp32 (fallback)
    float* Wp2  = Wp1 + 64 * 52;                 // 64 x 28
    float* Wp3  = Wp2 + 64 * 28;                 // 64 x 32
    unsigned short* Wb1 = (unsigned short*)(Wp3 + 64 * 32); // 64 x 64 bf16
    unsigned short* Wb2 = Wb1 + 64 * 64;                    // 32 x 64 bf16
    unsigned short* Wb3 = Wb2 + 32 * 64;                    // 32 x 64 bf16
    char* endp = (char*)(Wb3 + 32 * 64);

    size_t usedB   = (size_t)(endp - (char*)d_ws);
    size_t ebfOffB = (usedB + 127) & ~(size_t)127;
    size_t neededB = ebfOffB + (size_t)E * 128;  // ebf: E x 32 u32 (128B/row)
    const bool useBf = (ws_size >= neededB);
    unsigned* ebf = (unsigned*)((char*)d_ws + ebfOffB);

    // ---- pack W tables ----
    pack_we<64, 50, 52><<<(64 * 52 + 255) / 256, 256, 0, stream>>>(Wm1, Wp1);
    pack_we<50, 25, 28><<<(64 * 28 + 255) / 256, 256, 0, stream>>>(Wm2, Wp2);
    pack_we<25, 32, 32><<<(64 * 32 + 255) / 256, 256, 0, stream>>>(Wm3, Wp3);
    pack_wbt<64, 50, 64><<<(64 * 64 + 255) / 256, 256, 0, stream>>>(Wm1, Wb1);
    pack_wbt<50, 25, 32><<<(32 * 64 + 255) / 256, 256, 0, stream>>>(Wm2, Wb2);
    pack_wbt<25, 32, 32><<<(32 * 64 + 255) / 256, 256, 0, stream>>>(Wm3, Wb3);

    // ---- CSR build + fused bf16 convert/scatter ----
    hipMemsetAsync(counts, 0, (size_t)N * sizeof(int), stream);
    hist_kernel<<<2048, 256, 0, stream>>>(dst, counts, E);
    scan_block<<<SCAN_BLOCKS, 1024, 0, stream>>>(counts, cursor, bsums, N);
    scan_small<<<1, 64, 0, stream>>>(bsums, SCAN_BLOCKS);
    add_offsets<<<SCAN_BLOCKS, 1024, 0, stream>>>(cursor, bsums, N);
    cvt_scatter<<<E / 64, 256, 0, stream>>>(dst, src, efeats, cursor, recs,
                                            useBf ? ebf : nullptr);

    const int EB = E / 512;
    const int NB = (N + 255) / 256;

    // ---- g1 = nfeats @ Wm1(h-part) + bm1 ----
    gemv_g<64, 50, 52><<<NB, 256, 0, stream>>>(nfeats, Wm1, bm1, g, N);

    // ---- layer 1 ----
    hipMemsetAsync(agg, 0, (size_t)N * 52 * sizeof(float), stream);
    if (useBf)
        edge_mfma<50, 52, 4><<<EB, 256, 0, stream>>>(g, ebf, recs, Wb1, agg);
    else
        edge_fb<50, 52, 51><<<EB, 256, 0, stream>>>(g, efeats, recs, Wp1, agg);
    node_kernel<64, 64, 50, 50, 52, 25, 28><<<NB, 256, 0, stream>>>(
        nfeats, agg, Wa1, ba1, Wm2, bm2, h1, g, N);

    // ---- layer 2 ----
    hipMemsetAsync(agg, 0, (size_t)N * 52 * sizeof(float), stream);
    if (useBf)
        edge_mfma<25, 28, 2><<<EB, 256, 0, stream>>>(g, ebf, recs, Wb2, agg);
    else
        edge_fb<25, 28, 25><<<EB, 256, 0, stream>>>(g, efeats, recs, Wp2, agg);
    node_kernel<50, 52, 25, 25, 28, 32, 32><<<NB, 256, 0, stream>>>(
        h1, agg, Wa2, ba2, Wm3, bm3, h2, g, N);

    // ---- layer 3 ----
    hipMemsetAsync(agg, 0, (size_t)N * 52 * sizeof(float), stream);
    if (useBf)
        edge_mfma<32, 32, 2><<<EB, 256, 0, stream>>>(g, ebf, recs, Wb3, agg);
    else
        edge_fb<32, 32, 33><<<EB, 256, 0, stream>>>(g, efeats, recs, Wp3, agg);
    node_kernel<25, 28, 32, 32, 32, 0, 0><<<NB, 256, 0, stream>>>(
        h2, agg, Wa3, ba3, nullptr, nullptr, out, nullptr, N);
}

// Round 16
// 1291.867 us; speedup vs baseline: 1.2009x; 1.0058x over previous
//
#include <hip/hip_runtime.h>

#define DEVINL __device__ __forceinline__

typedef __attribute__((ext_vector_type(8))) short bf16x8;
typedef __attribute__((ext_vector_type(4))) float f32x4;

DEVINL void fma4(float4& a, const float4 w, const float x) {
    a.x += w.x * x; a.y += w.y * x; a.z += w.z * x; a.w += w.w * x;
}

DEVINL unsigned short bf16of(float x) {
    unsigned a = __float_as_uint(x);
    a += 0x7FFFu + ((a >> 16) & 1u);
    return (unsigned short)(a >> 16);
}

// pack two fp32 into one u32 of 2 bf16 (RNE); element "lo" in low half
DEVINL unsigned bfpair(float lo, float hi) {
    unsigned a = __float_as_uint(lo);
    a += 0x7FFFu + ((a >> 16) & 1u);
    unsigned b = __float_as_uint(hi);
    b += 0x7FFFu + ((b >> 16) & 1u);
    return (a >> 16) | (b & 0xFFFF0000u);
}

DEVINL bf16x8 as_bf16x8(uint4 u) {
    union { uint4 u4; bf16x8 b; } cv; cv.u4 = u; return cv.b;
}

// ===========================================================================
// CSR build: counting sort of edges by dst.
// ===========================================================================
__global__ __launch_bounds__(256) void hist_kernel(const int* __restrict__ d,
                                                   int* __restrict__ counts, int n) {
    for (int i = blockIdx.x * 256 + threadIdx.x; i < n; i += gridDim.x * 256)
        atomicAdd(&counts[d[i]], 1);
}

__global__ __launch_bounds__(1024) void scan_block(const int* __restrict__ in,
                                                   int* __restrict__ out,
                                                   int* __restrict__ bsums, int n) {
    __shared__ int buf[2][1024];
    const int t = threadIdx.x;
    const int i = blockIdx.x * 1024 + t;
    const int v = (i < n) ? in[i] : 0;
    int cur = 0;
    buf[0][t] = v;
    __syncthreads();
    #pragma unroll
    for (int s = 1; s < 1024; s <<= 1) {
        int x = buf[cur][t];
        if (t >= s) x += buf[cur][t - s];
        buf[cur ^ 1][t] = x;
        cur ^= 1;
        __syncthreads();
    }
    if (i < n) out[i] = buf[cur][t] - v;            // exclusive
    if (t == 1023) bsums[blockIdx.x] = buf[cur][t]; // block total
}

__global__ void scan_small(int* __restrict__ bs, int nb) {
    if (blockIdx.x == 0 && threadIdx.x == 0) {
        int acc = 0;
        for (int i = 0; i < nb; i++) { int v = bs[i]; bs[i] = acc; acc += v; }
    }
}

__global__ __launch_bounds__(1024) void add_offsets(int* __restrict__ out,
                                                    const int* __restrict__ bs, int n) {
    int i = blockIdx.x * 1024 + threadIdx.x;
    if (i < n) out[i] += bs[blockIdx.x];
}

// ===========================================================================
// cvt_scatter: fused CSR-scatter + bf16 convert. 4 lanes per edge.
// Sequential reads; random WRITES (fire-and-forget) carry the permutation.
// ===========================================================================
__global__ __launch_bounds__(256) void cvt_scatter(
    const int* __restrict__ dst,
    const int* __restrict__ src,
    const float* __restrict__ ef,
    int* __restrict__ cursor,
    int4* __restrict__ recs,
    unsigned* __restrict__ ebf)   // may be nullptr (fallback path)
{
    const int tid = threadIdx.x;
    const long long e = (long long)blockIdx.x * 64 + (tid >> 2);
    const int sub  = tid & 3;
    const int lane = tid & 63;

    const int dd = dst[e];
    const int ss = src[e];
    int pos = 0;
    if (sub == 0) pos = atomicAdd(&cursor[dd], 1);
    pos = __shfl(pos, lane & ~3);      // broadcast within the 4-lane group
    if (sub == 0) recs[pos] = make_int4((int)e, dd, ss, 0);

    if (ebf != nullptr) {
        const float4* erow = reinterpret_cast<const float4*>(ef + e * 64);
        float4 q0 = erow[sub * 4 + 0];
        float4 q1 = erow[sub * 4 + 1];
        float4 q2 = erow[sub * 4 + 2];
        float4 q3 = erow[sub * 4 + 3];
        uint4 o0, o1;
        o0.x = bfpair(q0.x, q0.y); o0.y = bfpair(q0.z, q0.w);
        o0.z = bfpair(q1.x, q1.y); o0.w = bfpair(q1.z, q1.w);
        o1.x = bfpair(q2.x, q2.y); o1.y = bfpair(q2.z, q2.w);
        o1.z = bfpair(q3.x, q3.y); o1.w = bfpair(q3.z, q3.w);
        uint4* outp = reinterpret_cast<uint4*>(ebf + (long long)pos * 32);
        outp[sub * 2]     = o0;
        outp[sub * 2 + 1] = o1;
    }
}

// ===========================================================================
// pack_we (fp32, fallback path): e-part rows -> padded [64][FOUTP].
// ===========================================================================
template<int FIN, int FOUT, int FOUTP>
__global__ __launch_bounds__(256) void pack_we(const float* __restrict__ W,
                                               float* __restrict__ Wp) {
    int idx = blockIdx.x * 256 + threadIdx.x;
    if (idx >= 64 * FOUTP) return;
    int k = idx / FOUTP, j = idx - k * FOUTP;
    Wp[idx] = (j < FOUT) ? W[(FIN + k) * FOUT + j] : 0.f;
}

// ===========================================================================
// pack_wbt: e-part of Wm -> bf16 TRANSPOSED table WbT[col][64].
// ===========================================================================
template<int FIN, int FOUT, int NC>
__global__ __launch_bounds__(256) void pack_wbt(const float* __restrict__ W,
                                                unsigned short* __restrict__ WbT) {
    int idx = blockIdx.x * 256 + threadIdx.x;
    if (idx >= NC * 64) return;
    int c = idx / 64, k = idx - c * 64;
    WbT[idx] = (c < FOUT) ? bf16of(W[(FIN + k) * FOUT + c]) : (unsigned short)0;
}

// ===========================================================================
// gemv_g: g = x @ W(h-part rows [0,FIN)) + b, padded to FOUTP.
// ===========================================================================
template<int FIN, int FOUT, int FOUTP>
__global__ __launch_bounds__(256) void gemv_g(
    const float* __restrict__ x,
    const float* __restrict__ W,
    const float* __restrict__ b,
    float* __restrict__ g, int nNodes)
{
    constexpr int F4 = FOUTP / 4;
    __shared__ float4 Wl[FIN * F4];
    __shared__ float  bl[FOUTP];
    const int tid = threadIdx.x;
    for (int idx = tid; idx < FIN * FOUTP; idx += 256) {
        int k = idx / FOUTP, j = idx - k * FOUTP;
        reinterpret_cast<float*>(Wl)[idx] = (j < FOUT) ? W[k * FOUT + j] : 0.f;
    }
    for (int idx = tid; idx < FOUTP; idx += 256)
        bl[idx] = (idx < FOUT) ? b[idx] : 0.f;
    __syncthreads();
    const int n = blockIdx.x * 256 + tid;
    if (n >= nNodes) return;
    float4 acc[F4];
    #pragma unroll
    for (int j4 = 0; j4 < F4; j4++) acc[j4] = reinterpret_cast<float4*>(bl)[j4];
    const float* xr = x + (long long)n * FIN;
    #pragma unroll 1
    for (int k = 0; k < FIN; ++k) {
        float xk = xr[k];
        const float4* wrow = &Wl[k * F4];
        #pragma unroll
        for (int j4 = 0; j4 < F4; j4++) fma4(acc[j4], wrow[j4], xk);
    }
    float4* gr = reinterpret_cast<float4*>(g + (long long)n * FOUTP);
    #pragma unroll
    for (int j4 = 0; j4 < F4; j4++) gr[j4] = acc[j4];
}

// ===========================================================================
// Unified edge kernel: m = relu(g[src] + e @ We). A-frags stream from the
// sorted bf16 ebf. r16 upgrades:
//   - NT==2 (L2/L3): g-values prefetched ONE CHUNK AHEAD (reduce hides the
//     L2 round trip) and HALF-WAVE SPLIT segmented reduce (lanes 0-31 walk
//     rows 0-15, lanes 32-63 rows 16-31; boundary-spanning segments emit
//     two partial atomics -- correct under atomicAdd). All 64 lanes busy.
//   - NT==4 (L1): r15 shape (52 cols need >32 lanes; VGPR-tighter).
// MFMA frag semantics HW-verified r11.
// ===========================================================================
template<int FOUT, int FOUTP, int NT>
__global__ __launch_bounds__(256) void edge_mfma(
    const float* __restrict__ g,
    const unsigned* __restrict__ ebf,      // [E][32] u32, sorted order
    const int4* __restrict__ recs,         // sorted {eid,dst,src,0}
    const unsigned short* __restrict__ WbT,
    float* __restrict__ agg)
{
    constexpr int MS = NT * 16 + 1;

    __shared__ float msg[4][32 * MS];
    __shared__ int sIdxL[512], dseg[512];

    const int tid = threadIdx.x;
    const long long pb = (long long)blockIdx.x * 512;
    {
        int4 r0 = recs[pb + tid];
        int4 r1 = recs[pb + 256 + tid];
        dseg[tid] = r0.y;  sIdxL[tid] = r0.z;
        dseg[tid + 256] = r1.y; sIdxL[tid + 256] = r1.z;
    }
    __syncthreads();

    const int lane = tid & 63;
    const int wv   = tid >> 6;
    const int lg   = lane >> 4;
    const int lc   = lane & 15;

    bf16x8 bfr[2][NT];
    #pragma unroll
    for (int kt = 0; kt < 2; kt++)
        #pragma unroll
        for (int nt = 0; nt < NT; nt++)
            bfr[kt][nt] = *reinterpret_cast<const bf16x8*>(
                WbT + (nt * 16 + lc) * 64 + kt * 32 + lg * 8);

    float* msgW = msg[wv];

    // prologue: chunk 0 A-frags
    bf16x8 a0[2], a1[2];
    #pragma unroll
    for (int mt = 0; mt < 2; mt++) {
        const unsigned* arow = ebf + (unsigned long long)(pb + wv * 128 + mt * 16 + lc) * 32;
        a0[mt] = *reinterpret_cast<const bf16x8*>(arow + lg * 4);
        a1[mt] = *reinterpret_cast<const bf16x8*>(arow + 16 + lg * 4);
    }
    // prologue: chunk 0 g-values (NT==2 keeps them pipelined across chunks)
    float gv[2][NT][4];
    {
        const int rb0 = wv * 128;
        #pragma unroll
        for (int mt = 0; mt < 2; mt++)
            #pragma unroll
            for (int nt = 0; nt < NT; nt++) {
                const int col = nt * 16 + lc;
                #pragma unroll
                for (int r = 0; r < 4; r++) {
                    int sr = sIdxL[rb0 + mt * 16 + lg * 4 + r];
                    gv[mt][nt][r] = (col < FOUT) ? g[(long long)sr * FOUTP + col] : 0.f;
                }
            }
    }

    #pragma unroll 1
    for (int ch = 0; ch < 4; ++ch) {
        const int rb0 = wv * 128 + ch * 32;

        // ---- compute both tiles into the msg tile ----
        #pragma unroll
        for (int mt = 0; mt < 2; mt++) {
            #pragma unroll
            for (int nt = 0; nt < NT; nt++) {
                f32x4 acc = {0.f, 0.f, 0.f, 0.f};
                acc = __builtin_amdgcn_mfma_f32_16x16x32_bf16(a0[mt], bfr[0][nt], acc, 0, 0, 0);
                acc = __builtin_amdgcn_mfma_f32_16x16x32_bf16(a1[mt], bfr[1][nt], acc, 0, 0, 0);
                const int col = nt * 16 + lc;
                #pragma unroll
                for (int r = 0; r < 4; r++)
                    msgW[(mt * 16 + lg * 4 + r) * MS + col] = fmaxf(acc[r] + gv[mt][nt][r], 0.f);
            }
        }

        // ---- prefetch next chunk's A-frags AND g-values (hidden by reduce) ----
        bf16x8 n0[2], n1[2];
        float gvn[2][NT][4];
        if (ch < 3) {
            const int rbn = wv * 128 + (ch + 1) * 32;
            #pragma unroll
            for (int mt = 0; mt < 2; mt++) {
                const unsigned* arow = ebf + (unsigned long long)(pb + rbn + mt * 16 + lc) * 32;
                n0[mt] = *reinterpret_cast<const bf16x8*>(arow + lg * 4);
                n1[mt] = *reinterpret_cast<const bf16x8*>(arow + 16 + lg * 4);
            }
            #pragma unroll
            for (int mt = 0; mt < 2; mt++)
                #pragma unroll
                for (int nt = 0; nt < NT; nt++) {
                    const int col = nt * 16 + lc;
                    #pragma unroll
                    for (int r = 0; r < 4; r++) {
                        int sr = sIdxL[rbn + mt * 16 + lg * 4 + r];
                        gvn[mt][nt][r] = (col < FOUT) ? g[(long long)sr * FOUTP + col] : 0.f;
                    }
                }
        }

        // ---- segmented reduce over this chunk's 32 rows ----
        const int base = rb0;
        if constexpr (NT == 2) {
            // half-wave split: lanes 0-31 -> rows 0-15, lanes 32-63 -> 16-31
            const int half = lane >> 5;
            const int hl   = lane & 31;
            const int rlo  = half * 16, rhi = rlo + 16;
            for (int r0 = rlo; r0 < rhi; ++r0) {
                int dr = dseg[base + r0];
                if (r0 > rlo && dseg[base + r0 - 1] == dr) continue;
                float s = 0.f;
                int rr = r0;
                while (true) {
                    s += msgW[rr * MS + hl];
                    ++rr;
                    if (rr >= rhi || dseg[base + rr] != dr) break;
                }
                if (hl < FOUT) atomicAdd(agg + (long long)dr * FOUT + hl, s);
            }
        } else {
            for (int r0 = 0; r0 < 32; ++r0) {
                int dr = dseg[base + r0];
                if (r0 > 0 && dseg[base + r0 - 1] == dr) continue;
                float s = 0.f;
                int rr = r0;
                while (true) {
                    if (lane < NT * 16) s += msgW[rr * MS + lane];
                    ++rr;
                    if (rr >= 32 || dseg[base + rr] != dr) break;
                }
                if (lane < FOUT) atomicAdd(agg + (long long)dr * FOUT + lane, s);
            }
        }

        if (ch < 3) {
            #pragma unroll
            for (int mt = 0; mt < 2; mt++) { a0[mt] = n0[mt]; a1[mt] = n1[mt]; }
            #pragma unroll
            for (int mt = 0; mt < 2; mt++)
                #pragma unroll
                for (int nt = 0; nt < NT; nt++)
                    #pragma unroll
                    for (int r = 0; r < 4; r++) gv[mt][nt][r] = gvn[mt][nt][r];
        }
    }
}

// ===========================================================================
// FALLBACK edge kernel (ws too small for ebf): round-10 proven structure.
// ===========================================================================
template<int FOUT, int FOUTP, int MS>
__global__ __launch_bounds__(256) void edge_fb(
    const float* __restrict__ g,
    const float* __restrict__ efeats,
    const int4* __restrict__ recs,
    const float* __restrict__ Wp,
    float* __restrict__ agg)
{
    constexpr int F4 = FOUTP / 4;
    constexpr int ST = 17;
    static_assert(128 * MS + 64 <= 512 * ST, "msg buf exceeds sbuf");

    __shared__ float sbuf[512 * ST];
    __shared__ int   dseg[512];

    const int tid = threadIdx.x;
    const long long pb = (long long)blockIdx.x * 512;
    int4 r0 = recs[pb + tid];
    int4 r1 = recs[pb + 256 + tid];
    dseg[tid] = r0.y;
    dseg[tid + 256] = r1.y;

    const float4* gr0 = reinterpret_cast<const float4*>(g + (long long)r0.z * FOUTP);
    const float4* gr1 = reinterpret_cast<const float4*>(g + (long long)r1.z * FOUTP);
    const float*  er0 = efeats + (long long)r0.x * 64;
    const float*  er1 = efeats + (long long)r1.x * 64;
    const float4* Wp4 = reinterpret_cast<const float4*>(Wp);

    float4 acc0[F4], acc1[F4];
    #pragma unroll
    for (int j4 = 0; j4 < F4; j4++) acc0[j4] = gr0[j4];
    #pragma unroll
    for (int j4 = 0; j4 < F4; j4++) acc1[j4] = gr1[j4];

    const int t0 = tid * ST;
    const int t1 = (tid + 256) * ST;

    for (int c = 0; c < 4; ++c) {
        const int off = c * 16;
        #pragma unroll
        for (int f = 0; f < 4; ++f) {
            float4 v0 = *reinterpret_cast<const float4*>(er0 + off + 4 * f);
            float4 v1 = *reinterpret_cast<const float4*>(er1 + off + 4 * f);
            float* d0 = &sbuf[t0 + 4 * f];
            float* d1 = &sbuf[t1 + 4 * f];
            d0[0] = v0.x; d0[1] = v0.y; d0[2] = v0.z; d0[3] = v0.w;
            d1[0] = v1.x; d1[1] = v1.y; d1[2] = v1.z; d1[3] = v1.w;
        }
        #pragma unroll 1
        for (int k = 0; k < 16; ++k) {
            const float x0 = sbuf[t0 + k];
            const float x1 = sbuf[t1 + k];
            const float4* wrow = &Wp4[(off + k) * F4];
            #pragma unroll
            for (int j4 = 0; j4 < F4; j4++) {
                float4 w = wrow[j4];
                fma4(acc0[j4], w, x0);
                fma4(acc1[j4], w, x1);
            }
        }
    }

    const int lane = tid & 63;
    const int wv   = tid >> 6;

    #pragma unroll 1
    for (int bb = 0; bb < 4; ++bb) {
        __syncthreads();
        if ((tid >> 7) == (bb & 1)) {
            const int r = tid & 127;
            float* mrow = &sbuf[r * MS];
            const float4* accp = (bb < 2) ? acc0 : acc1;
            #pragma unroll
            for (int j4 = 0; j4 < F4; j4++) {
                float4 a = accp[j4];
                if (4 * j4 + 0 < FOUT) mrow[4 * j4 + 0] = fmaxf(a.x, 0.f);
                if (4 * j4 + 1 < FOUT) mrow[4 * j4 + 1] = fmaxf(a.y, 0.f);
                if (4 * j4 + 2 < FOUT) mrow[4 * j4 + 2] = fmaxf(a.z, 0.f);
                if (4 * j4 + 3 < FOUT) mrow[4 * j4 + 3] = fmaxf(a.w, 0.f);
            }
        }
        __syncthreads();

        const int rbase = bb * 128;
        for (int r0i = wv * 32; r0i < wv * 32 + 32; ++r0i) {
            int dr = dseg[rbase + r0i];
            if (r0i > 0 && dseg[rbase + r0i - 1] == dr) continue;
            float s = 0.f;
            int rr = r0i;
            while (true) {
                s += sbuf[rr * MS + lane];
                ++rr;
                if (rr >= 128 || dseg[rbase + rr] != dr) break;
            }
            if (lane < FOUT) atomicAdd(agg + (long long)dr * FOUT + lane, s);
        }
    }
}

// ===========================================================================
// Node kernel (fused): h_next = relu(cat(h, agg) @ Wa + ba), plus fused
// g_next = h_next @ Wm_next(h-part) + bm_next when GOUT > 0.
// ===========================================================================
template<int FH, int FHP, int FAGG, int FOUT, int FOUTP, int GOUT, int GOUTP>
__global__ __launch_bounds__(256) void node_kernel(
    const float* __restrict__ h,
    const float* __restrict__ agg,
    const float* __restrict__ Wa,
    const float* __restrict__ ba,
    const float* __restrict__ Wmn,
    const float* __restrict__ bmn,
    float* __restrict__ out,
    float* __restrict__ gout,
    int nNodes)
{
    constexpr int K  = FH + FAGG;
    constexpr int F4 = FOUTP / 4;
    constexpr int G4 = (GOUT > 0) ? GOUTP / 4 : 1;

    __shared__ float4 Wl[K * F4];
    __shared__ float4 Wg[(GOUT > 0) ? FOUTP * G4 : 1];
    __shared__ float  bl[FOUTP];
    __shared__ float  bg[(GOUT > 0) ? GOUTP : 4];

    const int tid = threadIdx.x;
    for (int idx = tid; idx < K * FOUTP; idx += 256) {
        int k = idx / FOUTP, j = idx - k * FOUTP;
        reinterpret_cast<float*>(Wl)[idx] = (j < FOUT) ? Wa[k * FOUT + j] : 0.f;
    }
    for (int idx = tid; idx < FOUTP; idx += 256)
        bl[idx] = (idx < FOUT) ? ba[idx] : 0.f;
    if constexpr (GOUT > 0) {
        for (int idx = tid; idx < FOUTP * GOUTP; idx += 256) {
            int k = idx / GOUTP, j = idx - k * GOUTP;
            reinterpret_cast<float*>(Wg)[idx] =
                (k < FOUT && j < GOUT) ? Wmn[k * GOUT + j] : 0.f;
        }
        for (int idx = tid; idx < GOUTP; idx += 256)
            bg[idx] = (idx < GOUT) ? bmn[idx] : 0.f;
    }
    __syncthreads();

    const int n = blockIdx.x * 256 + tid;
    if (n >= nNodes) return;

    float4 acc[F4];
    #pragma unroll
    for (int j4 = 0; j4 < F4; j4++) acc[j4] = reinterpret_cast<float4*>(bl)[j4];

    const float* hrow = h + (long long)n * FHP;
    #pragma unroll 1
    for (int k = 0; k < FH; k++) {
        float xk = hrow[k];
        const float4* wrow = &Wl[k * F4];
        #pragma unroll
        for (int j4 = 0; j4 < F4; j4++) fma4(acc[j4], wrow[j4], xk);
    }
    const float* arow = agg + (long long)n * FAGG;
    #pragma unroll 1
    for (int k = 0; k < FAGG; k++) {
        float xk = arow[k];
        const float4* wrow = &Wl[(FH + k) * F4];
        #pragma unroll
        for (int j4 = 0; j4 < F4; j4++) fma4(acc[j4], wrow[j4], xk);
    }

    #pragma unroll
    for (int j4 = 0; j4 < F4; j4++) {
        acc[j4].x = fmaxf(acc[j4].x, 0.f);
        acc[j4].y = fmaxf(acc[j4].y, 0.f);
        acc[j4].z = fmaxf(acc[j4].z, 0.f);
        acc[j4].w = fmaxf(acc[j4].w, 0.f);
    }
    float4* orow = reinterpret_cast<float4*>(out + (long long)n * FOUTP);
    #pragma unroll
    for (int j4 = 0; j4 < F4; j4++) orow[j4] = acc[j4];

    if constexpr (GOUT > 0) {
        float4 gacc[G4];
        #pragma unroll
        for (int j4 = 0; j4 < G4; j4++) gacc[j4] = reinterpret_cast<float4*>(bg)[j4];
        #pragma unroll 1
        for (int k4 = 0; k4 < F4; ++k4) {
            float4 xv = acc[k4];
            #pragma unroll
            for (int c = 0; c < 4; ++c) {
                float xc = (c == 0) ? xv.x : (c == 1) ? xv.y : (c == 2) ? xv.z : xv.w;
                const float4* wrow = &Wg[(k4 * 4 + c) * G4];
                #pragma unroll
                for (int j4 = 0; j4 < G4; j4++) fma4(gacc[j4], wrow[j4], xc);
            }
        }
        float4* grow = reinterpret_cast<float4*>(gout + (long long)n * GOUTP);
        #pragma unroll
        for (int j4 = 0; j4 < G4; j4++) grow[j4] = gacc[j4];
    }
}

extern "C" void kernel_launch(void* const* d_in, const int* in_sizes, int n_in,
                              void* d_out, int out_size, void* d_ws, size_t ws_size,
                              hipStream_t stream)
{
    const float* nfeats = (const float*)d_in[0];
    const float* efeats = (const float*)d_in[1];
    const int*   src    = (const int*)d_in[2];
    const int*   dst    = (const int*)d_in[3];
    const float* Wm1 = (const float*)d_in[4],  *bm1 = (const float*)d_in[5];
    const float* Wa1 = (const float*)d_in[6],  *ba1 = (const float*)d_in[7];
    const float* Wm2 = (const float*)d_in[8],  *bm2 = (const float*)d_in[9];
    const float* Wa2 = (const float*)d_in[10], *ba2 = (const float*)d_in[11];
    const float* Wm3 = (const float*)d_in[12], *bm3 = (const float*)d_in[13];
    const float* Wa3 = (const float*)d_in[14], *ba3 = (const float*)d_in[15];
    float* out = (float*)d_out;

    constexpr int N = 100000;
    constexpr int E = 3200000;                      // % 512 == 0, % 64 == 0
    constexpr int SCAN_BLOCKS = (N + 1023) / 1024;  // 98

    float* ws   = (float*)d_ws;
    float* h1   = ws;                            // N x 52
    float* h2   = h1 + (size_t)N * 52;           // N x 28
    float* agg  = h2 + (size_t)N * 28;           // N x 52
    float* g    = agg + (size_t)N * 52;          // N x 52
    int* counts = (int*)(g + (size_t)N * 52);    // N
    int* cursor = counts + N;                    // N
    int* bsums  = cursor + N;                    // 128
    int4* recs  = (int4*)(bsums + 128);          // E x 16B
    float* Wp1  = (float*)(recs + E);            // 64 x 52 fp32 (fallback)
    float* Wp2  = Wp1 + 64 * 52;                 // 64 x 28
    float* Wp3  = Wp2 + 64 * 28;                 // 64 x 32
    unsigned short* Wb1 = (unsigned short*)(Wp3 + 64 * 32); // 64 x 64 bf16
    unsigned short* Wb2 = Wb1 + 64 * 64;                    // 32 x 64 bf16
    unsigned short* Wb3 = Wb2 + 32 * 64;                    // 32 x 64 bf16
    char* endp = (char*)(Wb3 + 32 * 64);

    size_t usedB   = (size_t)(endp - (char*)d_ws);
    size_t ebfOffB = (usedB + 127) & ~(size_t)127;
    size_t neededB = ebfOffB + (size_t)E * 128;  // ebf: E x 32 u32 (128B/row)
    const bool useBf = (ws_size >= neededB);
    unsigned* ebf = (unsigned*)((char*)d_ws + ebfOffB);

    // ---- pack W tables ----
    pack_we<64, 50, 52><<<(64 * 52 + 255) / 256, 256, 0, stream>>>(Wm1, Wp1);
    pack_we<50, 25, 28><<<(64 * 28 + 255) / 256, 256, 0, stream>>>(Wm2, Wp2);
    pack_we<25, 32, 32><<<(64 * 32 + 255) / 256, 256, 0, stream>>>(Wm3, Wp3);
    pack_wbt<64, 50, 64><<<(64 * 64 + 255) / 256, 256, 0, stream>>>(Wm1, Wb1);
    pack_wbt<50, 25, 32><<<(32 * 64 + 255) / 256, 256, 0, stream>>>(Wm2, Wb2);
    pack_wbt<25, 32, 32><<<(32 * 64 + 255) / 256, 256, 0, stream>>>(Wm3, Wb3);

    // ---- CSR build + fused bf16 convert/scatter ----
    hipMemsetAsync(counts, 0, (size_t)N * sizeof(int), stream);
    hist_kernel<<<2048, 256, 0, stream>>>(dst, counts, E);
    scan_block<<<SCAN_BLOCKS, 1024, 0, stream>>>(counts, cursor, bsums, N);
    scan_small<<<1, 64, 0, stream>>>(bsums, SCAN_BLOCKS);
    add_offsets<<<SCAN_BLOCKS, 1024, 0, stream>>>(cursor, bsums, N);
    cvt_scatter<<<E / 64, 256, 0, stream>>>(dst, src, efeats, cursor, recs,
                                            useBf ? ebf : nullptr);

    const int EB = E / 512;
    const int NB = (N + 255) / 256;

    // ---- g1 = nfeats @ Wm1(h-part) + bm1 ----
    gemv_g<64, 50, 52><<<NB, 256, 0, stream>>>(nfeats, Wm1, bm1, g, N);

    // ---- layer 1 ----
    hipMemsetAsync(agg, 0, (size_t)N * 52 * sizeof(float), stream);
    if (useBf)
        edge_mfma<50, 52, 4><<<EB, 256, 0, stream>>>(g, ebf, recs, Wb1, agg);
    else
        edge_fb<50, 52, 51><<<EB, 256, 0, stream>>>(g, efeats, recs, Wp1, agg);
    node_kernel<64, 64, 50, 50, 52, 25, 28><<<NB, 256, 0, stream>>>(
        nfeats, agg, Wa1, ba1, Wm2, bm2, h1, g, N);

    // ---- layer 2 ----
    hipMemsetAsync(agg, 0, (size_t)N * 52 * sizeof(float), stream);
    if (useBf)
        edge_mfma<25, 28, 2><<<EB, 256, 0, stream>>>(g, ebf, recs, Wb2, agg);
    else
        edge_fb<25, 28, 25><<<EB, 256, 0, stream>>>(g, efeats, recs, Wp2, agg);
    node_kernel<50, 52, 25, 25, 28, 32, 32><<<NB, 256, 0, stream>>>(
        h1, agg, Wa2, ba2, Wm3, bm3, h2, g, N);

    // ---- layer 3 ----
    hipMemsetAsync(agg, 0, (size_t)N * 52 * sizeof(float), stream);
    if (useBf)
        edge_mfma<32, 32, 2><<<EB, 256, 0, stream>>>(g, ebf, recs, Wb3, agg);
    else
        edge_fb<32, 32, 33><<<EB, 256, 0, stream>>>(g, efeats, recs, Wp3, agg);
    node_kernel<25, 28, 32, 32, 32, 0, 0><<<NB, 256, 0, stream>>>(
        h2, agg, Wa3, ba3, nullptr, nullptr, out, nullptr, N);
}